// Round 16
// baseline (832.622 us; speedup 1.0000x reference)
//
#include <hip/hip_runtime.h>
#include <hip/hip_bf16.h>
#include <math.h>

// ---------------------------------------------------------------------------
// GATv2 x2 + global_add_pool + MLP head.
// xl/xr as bf16 mirrors. k_fused: ea@We edge GEMM on MFMA (swapped operands:
// A=We cols, B=ea edges). Wsb LDS layout gives fully-contiguous 1KB wave reads
// (lm*64+lk*16 within a (cc,cg) block) and contiguous b128 staging writes ->
// bank-conflict-free. Self-logit folded into online-softmax aggregation.
// Machine model (R8-R10): waves/SIMD = 256/VGPR; never force 4 waves/EU on
// fat kernels (caps VGPR at 64 -> spill).
// ---------------------------------------------------------------------------

typedef __attribute__((ext_vector_type(8))) short short8v;
typedef __attribute__((ext_vector_type(4))) float f32x4;

__device__ __forceinline__ unsigned short f2bf(float f) {
    union { float f; unsigned u; } v; v.f = f;
    unsigned r = v.u + 0x7fff + ((v.u >> 16) & 1);
    return (unsigned short)(r >> 16);
}
__device__ __forceinline__ float bf2f(unsigned short b) {
    union { unsigned u; float f; } v; v.u = ((unsigned)b) << 16;
    return v.f;
}

__device__ __forceinline__ int xcd_swizzle(int bid, int nwg) {
    int sq = nwg >> 3, sr = nwg & 7;
    int xcd = bid & 7, idx = bid >> 3;
    return (xcd < sr ? xcd * (sq + 1) : sr * (sq + 1) + (xcd - sr) * sq) + idx;
}

__global__ void k_deg(const int* __restrict__ dst, int E, int* __restrict__ deg) {
    int e = blockIdx.x * blockDim.x + threadIdx.x;
    if (e < E) atomicAdd(&deg[dst[e]], 1);
}

// ---- multi-block exclusive scan: deg[N] -> row_ptr[N+1], woff[N] ----------
__global__ void k_scan1(const int* __restrict__ deg, int N,
                        int* __restrict__ incl, int* __restrict__ bsum) {
    __shared__ int ws4[4];
    const int tid = threadIdx.x;
    const int lane = tid & 63, w = tid >> 6;
    const int base = blockIdx.x * 2048;
    int v[8];
    int s = 0;
#pragma unroll
    for (int j = 0; j < 8; ++j) {
        int i = base + tid * 8 + j;
        v[j] = (i < N) ? deg[i] : 0;
        s += v[j];
    }
    int ps = s;
#pragma unroll
    for (int off = 1; off < 64; off <<= 1) {
        int t = __shfl_up(ps, off);
        if (lane >= off) ps += t;
    }
    if (lane == 63) ws4[w] = ps;
    __syncthreads();
    int woffs = 0;
#pragma unroll
    for (int k = 0; k < 4; ++k)
        if (k < w) woffs += ws4[k];
    int run = ps - s + woffs;
#pragma unroll
    for (int j = 0; j < 8; ++j) {
        run += v[j];
        int i = base + tid * 8 + j;
        if (i < N) incl[i] = run;
    }
    if (tid == 255) bsum[blockIdx.x] = run;
}

__global__ void k_scan2(int* __restrict__ bsum, int nb) {
    if (threadIdx.x == 0) {
        int c = 0;
        for (int k = 0; k < nb; ++k) { int t = bsum[k]; bsum[k] = c; c += t; }
    }
}

__global__ void k_scan3(const int* __restrict__ incl, const int* __restrict__ deg,
                        const int* __restrict__ boff, int N,
                        int* __restrict__ row_ptr, int* __restrict__ woff) {
    int i = blockIdx.x * blockDim.x + threadIdx.x;
    if (i < N) {
        int v = incl[i] + boff[i >> 11];
        row_ptr[i + 1] = v;
        woff[i] = v - deg[i];
        if (i == 0) row_ptr[0] = 0;
    }
}

// scatter edges into CSR order; also materialize src/dst in CSR order
__global__ void k_scatter(const int* __restrict__ src, const int* __restrict__ dst,
                          int E, int* __restrict__ woff, int* __restrict__ cidx,
                          int* __restrict__ s_csr, int* __restrict__ d_csr) {
    int e = blockIdx.x * blockDim.x + threadIdx.x;
    if (e < E) {
        int d = dst[e];
        int p = atomicAdd(&woff[d], 1);
        cidx[p] = e;
        s_csr[p] = src[e];
        d_csr[p] = d;
    }
}

// segmented sum of edge attrs per dst (CSR order): 32-lane group per node
__global__ void k_easeg(const float* __restrict__ ea, const int* __restrict__ cidx,
                        const int* __restrict__ row_ptr, int N,
                        float* __restrict__ easum) {
    const int t = blockIdx.x * blockDim.x + threadIdx.x;
    const int w = t >> 5;
    const int lane = threadIdx.x & 31;
    if (w >= N) return;
    const int beg = row_ptr[w], end = row_ptr[w + 1];
    float s = 0.f;
    for (int i = beg; i < end; ++i) {
        int e = cidx[i];
        s += ea[(size_t)e * 32 + lane];
    }
    easum[(size_t)w * 32 + lane] = s;
}

// ---- LDS-tiled GEMM: {xl,xr}[n][col] = in[n][:128] . W{l,r}[:, col] + b ----
// outputs bf16 mirrors (gathered later by k_fused/k_aggr)
template <int HC>
__global__ __launch_bounds__(256, 2) void k_xw(
        const float* __restrict__ in, int N,
        const float* __restrict__ Wl, const float* __restrict__ bl,
        const float* __restrict__ Wr, const float* __restrict__ br,
        unsigned short* __restrict__ outl, unsigned short* __restrict__ outr) {
    __shared__ float Xs[128][68];  // [k][row], +4 pad
    __shared__ float Ws[128][64];  // [k][col]
    const int tid = threadIdx.x;
    const int m0 = blockIdx.x * 64;
    const int cc = blockIdx.y;

#pragma unroll
    for (int t = 0; t < 8; ++t) {
        int idx4 = tid + t * 256;
        int r = idx4 >> 5, k4 = idx4 & 31;
        int n = m0 + r;
        float4 v = make_float4(0.f, 0.f, 0.f, 0.f);
        if (n < N) v = ((const float4*)in)[(size_t)n * 32 + k4];
        Xs[k4 * 4 + 0][r] = v.x;
        Xs[k4 * 4 + 1][r] = v.y;
        Xs[k4 * 4 + 2][r] = v.z;
        Xs[k4 * 4 + 3][r] = v.w;
    }

    const int rm = tid >> 4, rn = tid & 15;
    float acc[4][4];

#pragma unroll
    for (int mat = 0; mat < 2; ++mat) {
        const float* W = mat ? Wr : Wl;
        const float* b = mat ? br : bl;
        unsigned short* out = mat ? outr : outl;
        __syncthreads();
#pragma unroll
        for (int i = tid; i < 128 * 64; i += 256) {
            int k = i >> 6, c = i & 63;
            Ws[k][c] = W[(size_t)k * HC + cc * 64 + c];
        }
        __syncthreads();
#pragma unroll
        for (int i = 0; i < 4; ++i)
#pragma unroll
            for (int j = 0; j < 4; ++j) acc[i][j] = 0.f;
#pragma unroll 8
        for (int k = 0; k < 128; ++k) {
            float4 a = *(const float4*)&Xs[k][rm * 4];
            float4 bv = *(const float4*)&Ws[k][rn * 4];
            acc[0][0] += a.x * bv.x; acc[0][1] += a.x * bv.y;
            acc[0][2] += a.x * bv.z; acc[0][3] += a.x * bv.w;
            acc[1][0] += a.y * bv.x; acc[1][1] += a.y * bv.y;
            acc[1][2] += a.y * bv.z; acc[1][3] += a.y * bv.w;
            acc[2][0] += a.z * bv.x; acc[2][1] += a.z * bv.y;
            acc[2][2] += a.z * bv.z; acc[2][3] += a.z * bv.w;
            acc[3][0] += a.w * bv.x; acc[3][1] += a.w * bv.y;
            acc[3][2] += a.w * bv.z; acc[3][3] += a.w * bv.w;
        }
        float4 bb = *(const float4*)&b[cc * 64 + rn * 4];
#pragma unroll
        for (int i = 0; i < 4; ++i) {
            int n = m0 + rm * 4 + i;
            if (n < N) {
                ushort4 o;
                o.x = f2bf(acc[i][0] + bb.x);
                o.y = f2bf(acc[i][1] + bb.y);
                o.z = f2bf(acc[i][2] + bb.z);
                o.w = f2bf(acc[i][3] + bb.w);
                *(ushort4*)&out[(size_t)n * HC + cc * 64 + rn * 4] = o;
            }
        }
    }
}

// ---- EE GEMM (self-loop path): out[m][col] = A[m][:32] . We[:, col] --------
template <int HC>
__global__ __launch_bounds__(256, 2) void k_ee(
        const float* __restrict__ A, int M,
        const float* __restrict__ We,
        float* __restrict__ out) {
    __shared__ float As[32][68];
    __shared__ float Ws[32][64];
    const int tid = threadIdx.x;
    const int m0 = blockIdx.x * 64;
    const int cc = blockIdx.y;

#pragma unroll
    for (int t = 0; t < 2; ++t) {
        int idx4 = tid + t * 256;
        int r = idx4 >> 3, q = idx4 & 7;
        int n = m0 + r;
        float4 v = make_float4(0.f, 0.f, 0.f, 0.f);
        if (n < M) v = ((const float4*)A)[(size_t)n * 8 + q];
        As[q * 4 + 0][r] = v.x;
        As[q * 4 + 1][r] = v.y;
        As[q * 4 + 2][r] = v.z;
        As[q * 4 + 3][r] = v.w;
    }
#pragma unroll
    for (int i = tid; i < 32 * 64; i += 256) {
        int k = i >> 6, c = i & 63;
        Ws[k][c] = We[(size_t)k * HC + cc * 64 + c];
    }
    __syncthreads();

    const int rm = tid >> 4, rn = tid & 15;
    float acc[4][4];
#pragma unroll
    for (int i = 0; i < 4; ++i)
#pragma unroll
        for (int j = 0; j < 4; ++j) acc[i][j] = 0.f;
#pragma unroll
    for (int k = 0; k < 32; ++k) {
        float4 a = *(const float4*)&As[k][rm * 4];
        float4 bv = *(const float4*)&Ws[k][rn * 4];
        acc[0][0] += a.x * bv.x; acc[0][1] += a.x * bv.y;
        acc[0][2] += a.x * bv.z; acc[0][3] += a.x * bv.w;
        acc[1][0] += a.y * bv.x; acc[1][1] += a.y * bv.y;
        acc[1][2] += a.y * bv.z; acc[1][3] += a.y * bv.w;
        acc[2][0] += a.z * bv.x; acc[2][1] += a.z * bv.y;
        acc[2][2] += a.z * bv.z; acc[2][3] += a.z * bv.w;
        acc[3][0] += a.w * bv.x; acc[3][1] += a.w * bv.y;
        acc[3][2] += a.w * bv.z; acc[3][3] += a.w * bv.w;
    }
#pragma unroll
    for (int i = 0; i < 4; ++i) {
        int n = m0 + rm * 4 + i;
        if (n < M) {
            float4 o = make_float4(acc[i][0], acc[i][1], acc[i][2], acc[i][3]);
            *(float4*)&out[(size_t)n * HC + cc * 64 + rn * 4] = o;
        }
    }
}

// ---- fused edge logits in CSR order, swapped-MFMA, conflict-free LDS --------
// 64 edges/block, 4 waves; wave w owns edges [w*16, w*16+16).
// D = A(We cols 16) x B(ea edges 16), K=32 full, one MFMA per (head, cg).
// Wsb layout (shorts): [(cc*4+cg)*512 + lm*32 + lk*8] -> per (cc,cg) the wave
//   reads a CONTIGUOUS 1KB block (lane offset lm*64+lk*16); staging writes are
//   contiguous 16B per work-item p at p*16 bytes.
// B-frag: lane holds ea[edge = w*16 + (l&15)][k = lk*8 + j]  (loaded ONCE).
// D: lane holds 4 consecutive weight cols (cg*16 + lk*4 + r) x 1 edge (l&15)
//   -> ushort4 xl/xr gathers, float4 att, 2-shuffle (16,32) per-edge reduce.
template <int H>
__global__ __launch_bounds__(256, 2) void k_fused(
        const unsigned short* __restrict__ xlb, const unsigned short* __restrict__ xrb,
        const float* __restrict__ ea,
        const int* __restrict__ cidx, const int* __restrict__ s_csr,
        const int* __restrict__ d_csr, int E,
        const float* __restrict__ We, const float* __restrict__ att,
        float* __restrict__ alpha) {
    constexpr int HC = H * 64;
    __shared__ __align__(16) unsigned short Wsb[HC * 32];  // see layout above
    __shared__ int Es[64], Ss[64], Ds[64];
    const int tid = threadIdx.x;
    const int wg = xcd_swizzle(blockIdx.x, gridDim.x);
    const int i0 = wg * 64;

    if (tid < 64) {
        int i = i0 + tid;
        bool ok = i < E;
        Es[tid] = ok ? cidx[i] : 0;
        Ss[tid] = ok ? s_csr[i] : 0;
        Ds[tid] = ok ? d_csr[i] : 0;
    }
    // stage We as bf16: work-item p = col*4 + lk2 writes short8 at p*8 shorts
    // (contiguous b128 writes). Content: We[lk2*8+j][col], j=0..7.
    for (int p = tid; p < HC * 4; p += 256) {
        int col = p >> 2, lk2 = p & 3;
        short8v v;
#pragma unroll
        for (int j = 0; j < 8; ++j)
            v[j] = (short)f2bf(We[(size_t)(lk2 * 8 + j) * HC + col]);
        *(short8v*)&Wsb[(size_t)p * 8] = v;
    }
    __syncthreads();

    const int lane = tid & 63;
    const int w = tid >> 6;
    const int lm = lane & 15;   // edge within wave (D col); A row within cg tile
    const int lk = lane >> 4;   // k-chunk; D row group
    const int k0 = lk * 8;

    const int el = w * 16 + lm;
    const int eidx = Es[el];
    const int sN = Ss[el], dN = Ds[el];
    const bool ok = (i0 + el) < E;

    // B fragment: this lane's edge ea row, k = k0..k0+7 (bf16), loaded once
    short8v bfrag;
    {
        const float4* bp = (const float4*)(ea + (size_t)eidx * 32 + k0);
        float4 v0 = bp[0], v1 = bp[1];
        bfrag[0] = (short)f2bf(v0.x); bfrag[1] = (short)f2bf(v0.y);
        bfrag[2] = (short)f2bf(v0.z); bfrag[3] = (short)f2bf(v0.w);
        bfrag[4] = (short)f2bf(v1.x); bfrag[5] = (short)f2bf(v1.y);
        bfrag[6] = (short)f2bf(v1.z); bfrag[7] = (short)f2bf(v1.w);
    }

#pragma unroll
    for (int cc = 0; cc < H; ++cc) {
        float part = 0.f;
#pragma unroll
        for (int cg = 0; cg < 4; ++cg) {
            // A-frag: We col = cc*64+cg*16+lm, k = lk*8..+8 ->
            // Wsb index (cc*4+cg)*512 + lm*32 + lk*8  (contiguous 1KB/wave)
            short8v afrag =
                *(const short8v*)&Wsb[((cc * 4 + cg) << 9) + (lm << 5) + (lk << 3)];
            f32x4 dacc = {0.f, 0.f, 0.f, 0.f};
            dacc = __builtin_amdgcn_mfma_f32_16x16x32_bf16(afrag, bfrag, dacc, 0, 0, 0);
            const int col0 = cc * 64 + cg * 16 + lk * 4;  // this lane's 4 D-rows
            ushort4 xa = *(const ushort4*)&xlb[(size_t)sN * HC + col0];
            ushort4 xb = *(const ushort4*)&xrb[(size_t)dN * HC + col0];
            float4 at4 = *(const float4*)&att[col0];
            float m0 = bf2f(xa.x) + bf2f(xb.x) + dacc[0];
            float m1 = bf2f(xa.y) + bf2f(xb.y) + dacc[1];
            float m2 = bf2f(xa.z) + bf2f(xb.z) + dacc[2];
            float m3 = bf2f(xa.w) + bf2f(xb.w) + dacc[3];
            m0 = m0 > 0.f ? m0 : 0.2f * m0;
            m1 = m1 > 0.f ? m1 : 0.2f * m1;
            m2 = m2 > 0.f ? m2 : 0.2f * m2;
            m3 = m3 > 0.f ? m3 : 0.2f * m3;
            part += m0 * at4.x + m1 * at4.y + m2 * at4.z + m3 * at4.w;
        }
        // reduce over the 4 lk groups (lanes lm, lm+16, lm+32, lm+48)
        part += __shfl_xor(part, 16);
        part += __shfl_xor(part, 32);
        if (lk == 0 && ok) alpha[(size_t)(i0 + el) * H + cc] = part;
    }
}

// online-softmax aggregate over CSR segment, self-logit computed inline.
// One wave per node, lane = channel, 4-edge unroll; xl/xr gathered as bf16.
template <int H, bool RELU>
__global__ __launch_bounds__(256, 2) void k_aggr(
        const unsigned short* __restrict__ xlb, const unsigned short* __restrict__ xrb,
        const float* __restrict__ EEself, const int* __restrict__ deg,
        const float* __restrict__ att,
        const int* __restrict__ s_csr, const int* __restrict__ row_ptr,
        const float* __restrict__ alpha,
        const float* __restrict__ bias, int Nn,
        float* __restrict__ out) {
    constexpr int HC = H * 64;
    const int lane = threadIdx.x & 63;
    const int wg = xcd_swizzle(blockIdx.x, gridDim.x);
    const int n = wg * 4 + ((int)threadIdx.x >> 6);
    if (n >= Nn) return;

    // ---- self-loop logit, seeds the online softmax ----
    float m[H], den[H], acc[H];
    {
        int dg = deg[n];
        float inv = 1.f / (float)(dg > 0 ? dg : 1);
        float al[H];
#pragma unroll
        for (int h = 0; h < H; ++h) {
            float xlv = bf2f(xlb[(size_t)n * HC + h * 64 + lane]);
            float v = xlv + bf2f(xrb[(size_t)n * HC + h * 64 + lane])
                    + EEself[(size_t)n * HC + h * 64 + lane] * inv;
            v = v > 0.f ? v : 0.2f * v;
            al[h] = v * att[h * 64 + lane];
            acc[h] = xlv;
        }
#pragma unroll
        for (int off = 1; off < 64; off <<= 1)
#pragma unroll
            for (int h = 0; h < H; ++h) al[h] += __shfl_xor(al[h], off);
#pragma unroll
        for (int h = 0; h < H; ++h) { m[h] = al[h]; den[h] = 1.f; }
    }

    const int beg = row_ptr[n], end = row_ptr[n + 1];
    int i = beg;
    for (; i + 3 < end; i += 4) {
        int s0 = s_csr[i], s1 = s_csr[i + 1], s2 = s_csr[i + 2], s3 = s_csr[i + 3];
        float a0[H], a1[H], a2[H], a3[H], xv0[H], xv1[H], xv2[H], xv3[H];
#pragma unroll
        for (int h = 0; h < H; ++h) {
            a0[h] = alpha[(size_t)i * H + h];
            a1[h] = alpha[(size_t)(i + 1) * H + h];
            a2[h] = alpha[(size_t)(i + 2) * H + h];
            a3[h] = alpha[(size_t)(i + 3) * H + h];
            xv0[h] = bf2f(xlb[(size_t)s0 * HC + h * 64 + lane]);
            xv1[h] = bf2f(xlb[(size_t)s1 * HC + h * 64 + lane]);
            xv2[h] = bf2f(xlb[(size_t)s2 * HC + h * 64 + lane]);
            xv3[h] = bf2f(xlb[(size_t)s3 * HC + h * 64 + lane]);
        }
#pragma unroll
        for (int h = 0; h < H; ++h) {
            float mx01 = fmaxf(a0[h], a1[h]);
            float mx23 = fmaxf(a2[h], a3[h]);
            float nm = fmaxf(m[h], fmaxf(mx01, mx23));
            float corr = __expf(m[h] - nm);
            float p0 = __expf(a0[h] - nm);
            float p1 = __expf(a1[h] - nm);
            float p2 = __expf(a2[h] - nm);
            float p3 = __expf(a3[h] - nm);
            den[h] = den[h] * corr + (p0 + p1) + (p2 + p3);
            acc[h] = acc[h] * corr + (p0 * xv0[h] + p1 * xv1[h])
                                   + (p2 * xv2[h] + p3 * xv3[h]);
            m[h] = nm;
        }
    }
    for (; i < end; ++i) {
        int s = s_csr[i];
#pragma unroll
        for (int h = 0; h < H; ++h) {
            float a = alpha[(size_t)i * H + h];
            float xv = bf2f(xlb[(size_t)s * HC + h * 64 + lane]);
            float nm = fmaxf(m[h], a);
            float corr = __expf(m[h] - nm);
            float p = __expf(a - nm);
            den[h] = den[h] * corr + p;
            acc[h] = acc[h] * corr + p * xv;
            m[h] = nm;
        }
    }
#pragma unroll
    for (int h = 0; h < H; ++h) {
        float r = acc[h] / den[h] + bias[h * 64 + lane];
        if (RELU) r = r > 0.f ? r : 0.01f * r;
        out[(size_t)n * HC + h * 64 + lane] = r;
    }
}

// global_add_pool over sorted batch
__global__ void k_pool(const float* __restrict__ h2, const int* __restrict__ batch,
                       int Nn, float* __restrict__ g) {
    const int c = threadIdx.x;  // 0..191
    const int n0 = blockIdx.x * 128;
    if (n0 >= Nn) return;
    const int n1 = (n0 + 128 < Nn) ? n0 + 128 : Nn;
    float s = 0.f;
    int cur = batch[n0];
    for (int n = n0; n < n1; ++n) {
        int b = batch[n];
        if (b != cur) {
            atomicAdd(&g[cur * 192 + c], s);
            s = 0.f;
            cur = b;
        }
        s += h2[(size_t)n * 192 + c];
    }
    atomicAdd(&g[cur * 192 + c], s);
}

__global__ void k_mlp(const float* __restrict__ g,
                      const float* W1, const float* c1, const float* W2, const float* c2,
                      const float* W3, const float* c3, const float* W4, const float* c4,
                      const float* W5, const float* c5, const float* W6, const float* c6,
                      float* __restrict__ out) {
    __shared__ float t0[8 * 192];
    __shared__ float t1[8 * 64];
    __shared__ float t2[8 * 32];
    __shared__ float t3[8 * 16];
    __shared__ float t4[8 * 8];
    const int tid = threadIdx.x;
    for (int i = tid; i < 8 * 192; i += 256) t0[i] = g[i];
    __syncthreads();
    for (int i = tid; i < 8 * 64; i += 256) {
        int r = i >> 6, c = i & 63;
        float s = c1[c];
        for (int k = 0; k < 192; ++k) s += t0[r * 192 + k] * W1[k * 64 + c];
        t1[i] = s > 0.f ? s : 0.01f * s;
    }
    __syncthreads();
    for (int i = tid; i < 8 * 32; i += 256) {
        int r = i >> 5, c = i & 31;
        float s = c2[c];
        for (int k = 0; k < 64; ++k) s += t1[r * 64 + k] * W2[k * 32 + c];
        t2[i] = s > 0.f ? s : 0.01f * s;
    }
    __syncthreads();
    for (int i = tid; i < 8 * 16; i += 256) {
        int r = i >> 4, c = i & 15;
        float s = c3[c];
        for (int k = 0; k < 32; ++k) s += t2[r * 32 + k] * W3[k * 16 + c];
        t3[i] = s > 0.f ? s : 0.01f * s;
    }
    __syncthreads();
    for (int i = tid; i < 8 * 8; i += 256) {
        int r = i >> 3, c = i & 7;
        float s = c4[c];
        for (int k = 0; k < 16; ++k) s += t3[r * 16 + k] * W4[k * 8 + c];
        t4[i] = s > 0.f ? s : 0.01f * s;
    }
    __syncthreads();
    if (tid < 8) {
        float s = c5[0];
        for (int k = 0; k < 8; ++k) s += t4[tid * 8 + k] * W5[k];
        s = s * W6[0] + c6[0];
        out[tid] = s;
    }
}

extern "C" void kernel_launch(void* const* d_in, const int* in_sizes, int n_in,
                              void* d_out, int out_size, void* d_ws, size_t ws_size,
                              hipStream_t stream) {
    const float* x     = (const float*)d_in[0];
    const int*   eidx  = (const int*)d_in[1];
    const float* ea    = (const float*)d_in[2];
    const int*   batch = (const int*)d_in[3];
    const float* Wl1 = (const float*)d_in[4];
    const float* bl1 = (const float*)d_in[5];
    const float* Wr1 = (const float*)d_in[6];
    const float* br1 = (const float*)d_in[7];
    const float* We1 = (const float*)d_in[8];
    const float* att1 = (const float*)d_in[9];
    const float* bias1 = (const float*)d_in[10];
    const float* Wl2 = (const float*)d_in[11];
    const float* bl2 = (const float*)d_in[12];
    const float* Wr2 = (const float*)d_in[13];
    const float* br2 = (const float*)d_in[14];
    const float* We2 = (const float*)d_in[15];
    const float* att2 = (const float*)d_in[16];
    const float* bias2 = (const float*)d_in[17];
    const float* W1 = (const float*)d_in[18];
    const float* c1 = (const float*)d_in[19];
    const float* W2 = (const float*)d_in[20];
    const float* c2 = (const float*)d_in[21];
    const float* W3 = (const float*)d_in[22];
    const float* c3 = (const float*)d_in[23];
    const float* W4 = (const float*)d_in[24];
    const float* c4 = (const float*)d_in[25];
    const float* W5 = (const float*)d_in[26];
    const float* c5 = (const float*)d_in[27];
    const float* W6 = (const float*)d_in[28];
    const float* c6 = (const float*)d_in[29];

    const int N = in_sizes[0] / 128;
    const int E = in_sizes[1] / 2;
    const int* srcs = eidx;
    const int* dsts = eidx + E;

    char* p = (char*)d_ws;
    auto alloc = [&](size_t bytes) -> char* {
        char* r = p;
        p += (bytes + 255) & ~(size_t)255;
        return r;
    };
    int*            deg     = (int*)alloc((size_t)N * 4);
    int*            row_ptr = (int*)alloc((size_t)(N + 1) * 4);
    int*            woff    = (int*)alloc((size_t)N * 4);
    int*            cidx    = (int*)alloc((size_t)E * 4);
    int*            s_csr   = (int*)alloc((size_t)E * 4);
    int*            d_csr   = (int*)alloc((size_t)E * 4);
    int*            incl    = (int*)alloc((size_t)N * 4);
    int*            bsum    = (int*)alloc(64 * 4);
    float*          easum   = (float*)alloc((size_t)N * 32 * 4);
    float*          EEself  = (float*)alloc((size_t)N * 192 * 4);
    unsigned short* xlb     = (unsigned short*)alloc((size_t)N * 192 * 2);
    unsigned short* xrb     = (unsigned short*)alloc((size_t)N * 192 * 2);
    float*          h1      = (float*)alloc((size_t)N * 128 * 4);
    float*          h2      = (float*)alloc((size_t)N * 192 * 4);
    float*          alpha   = (float*)alloc((size_t)E * 3 * 4);
    float*          gp      = (float*)alloc(8 * 192 * 4);

    hipMemsetAsync(deg, 0, (size_t)N * 4, stream);
    hipMemsetAsync(gp, 0, 8 * 192 * 4, stream);

    // CSR build
    const int nb = (N + 2047) / 2048;
    k_deg<<<(E + 255) / 256, 256, 0, stream>>>(dsts, E, deg);
    k_scan1<<<nb, 256, 0, stream>>>(deg, N, incl, bsum);
    k_scan2<<<1, 64, 0, stream>>>(bsum, nb);
    k_scan3<<<(N + 255) / 256, 256, 0, stream>>>(incl, deg, bsum, N, row_ptr, woff);
    k_scatter<<<(E + 255) / 256, 256, 0, stream>>>(srcs, dsts, E, woff, cidx, s_csr, d_csr);

    const int mt = (N + 63) / 64;   // GEMM row tiles
    const int et = (E + 63) / 64;   // fused edge tiles (64 edges/block)
    const int nblk = (N + 3) / 4;   // node-parallel blocks (1 wave/node)

    k_easeg<<<(N * 32 + 255) / 256, 256, 0, stream>>>(ea, cidx, row_ptr, N, easum);

    // ---------------- conv1: H=2, HC=128 ----------------
    k_xw<128><<<dim3(mt, 2), 256, 0, stream>>>(x, N, Wl1, bl1, Wr1, br1, xlb, xrb);
    k_ee<128><<<dim3(mt, 2), 256, 0, stream>>>(easum, N, We1, EEself);
    k_fused<2><<<et, 256, 0, stream>>>(xlb, xrb, ea, cidx, s_csr, d_csr, E, We1, att1, alpha);
    k_aggr<2, true><<<nblk, 256, 0, stream>>>(xlb, xrb, EEself, deg, att1, s_csr, row_ptr,
                                              alpha, bias1, N, h1);

    // ---------------- conv2: H=3, HC=192 ----------------
    k_xw<192><<<dim3(mt, 3), 256, 0, stream>>>(h1, N, Wl2, bl2, Wr2, br2, xlb, xrb);
    k_ee<192><<<dim3(mt, 3), 256, 0, stream>>>(easum, N, We2, EEself);
    k_fused<3><<<et, 256, 0, stream>>>(xlb, xrb, ea, cidx, s_csr, d_csr, E, We2, att2, alpha);
    k_aggr<3, true><<<nblk, 256, 0, stream>>>(xlb, xrb, EEself, deg, att2, s_csr, row_ptr,
                                              alpha, bias2, N, h2);

    k_pool<<<(N + 127) / 128, 192, 0, stream>>>(h2, batch, N, gp);
    k_mlp<<<1, 256, 0, stream>>>(gp, W1, c1, W2, c2, W3, c3, W4, c4, W5, c5, W6, c6,
                                 (float*)d_out);
}

// Round 17
// 714.332 us; speedup vs baseline: 1.1656x; 1.1656x over previous
//
#include <hip/hip_runtime.h>
#include <hip/hip_bf16.h>
#include <math.h>

// ---------------------------------------------------------------------------
// GATv2 x2 + global_add_pool + MLP head.
// xl/xr as bf16 mirrors. k_fused: R13-validated MFMA edge kernel (A=ea edges,
// B=We cols in LDS, D = 1 col x 4 edges -> column-coalesced gathers; 136us
// measured; bank-conflict counter high but NOT on critical path - R16 proved
// removing them costs more elsewhere). k_xw: MFMA GEMM using the same
// HW-verified fragment maps. Self-logit folded into online-softmax aggr.
// Machine model (R8-R10): waves/SIMD = 256/VGPR; never force 4 waves/EU.
// ---------------------------------------------------------------------------

typedef __attribute__((ext_vector_type(8))) short short8v;
typedef __attribute__((ext_vector_type(4))) float f32x4;

__device__ __forceinline__ unsigned short f2bf(float f) {
    union { float f; unsigned u; } v; v.f = f;
    unsigned r = v.u + 0x7fff + ((v.u >> 16) & 1);
    return (unsigned short)(r >> 16);
}
__device__ __forceinline__ float bf2f(unsigned short b) {
    union { unsigned u; float f; } v; v.u = ((unsigned)b) << 16;
    return v.f;
}

__device__ __forceinline__ int xcd_swizzle(int bid, int nwg) {
    int sq = nwg >> 3, sr = nwg & 7;
    int xcd = bid & 7, idx = bid >> 3;
    return (xcd < sr ? xcd * (sq + 1) : sr * (sq + 1) + (xcd - sr) * sq) + idx;
}

__global__ void k_deg(const int* __restrict__ dst, int E, int* __restrict__ deg) {
    int e = blockIdx.x * blockDim.x + threadIdx.x;
    if (e < E) atomicAdd(&deg[dst[e]], 1);
}

// ---- multi-block exclusive scan: deg[N] -> row_ptr[N+1], woff[N] ----------
__global__ void k_scan1(const int* __restrict__ deg, int N,
                        int* __restrict__ incl, int* __restrict__ bsum) {
    __shared__ int ws4[4];
    const int tid = threadIdx.x;
    const int lane = tid & 63, w = tid >> 6;
    const int base = blockIdx.x * 2048;
    int v[8];
    int s = 0;
#pragma unroll
    for (int j = 0; j < 8; ++j) {
        int i = base + tid * 8 + j;
        v[j] = (i < N) ? deg[i] : 0;
        s += v[j];
    }
    int ps = s;
#pragma unroll
    for (int off = 1; off < 64; off <<= 1) {
        int t = __shfl_up(ps, off);
        if (lane >= off) ps += t;
    }
    if (lane == 63) ws4[w] = ps;
    __syncthreads();
    int woffs = 0;
#pragma unroll
    for (int k = 0; k < 4; ++k)
        if (k < w) woffs += ws4[k];
    int run = ps - s + woffs;
#pragma unroll
    for (int j = 0; j < 8; ++j) {
        run += v[j];
        int i = base + tid * 8 + j;
        if (i < N) incl[i] = run;
    }
    if (tid == 255) bsum[blockIdx.x] = run;
}

__global__ void k_scan2(int* __restrict__ bsum, int nb) {
    if (threadIdx.x == 0) {
        int c = 0;
        for (int k = 0; k < nb; ++k) { int t = bsum[k]; bsum[k] = c; c += t; }
    }
}

__global__ void k_scan3(const int* __restrict__ incl, const int* __restrict__ deg,
                        const int* __restrict__ boff, int N,
                        int* __restrict__ row_ptr, int* __restrict__ woff) {
    int i = blockIdx.x * blockDim.x + threadIdx.x;
    if (i < N) {
        int v = incl[i] + boff[i >> 11];
        row_ptr[i + 1] = v;
        woff[i] = v - deg[i];
        if (i == 0) row_ptr[0] = 0;
    }
}

// scatter edges into CSR order; also materialize src/dst in CSR order
__global__ void k_scatter(const int* __restrict__ src, const int* __restrict__ dst,
                          int E, int* __restrict__ woff, int* __restrict__ cidx,
                          int* __restrict__ s_csr, int* __restrict__ d_csr) {
    int e = blockIdx.x * blockDim.x + threadIdx.x;
    if (e < E) {
        int d = dst[e];
        int p = atomicAdd(&woff[d], 1);
        cidx[p] = e;
        s_csr[p] = src[e];
        d_csr[p] = d;
    }
}

// segmented sum of edge attrs per dst (CSR order): 32-lane group per node
__global__ void k_easeg(const float* __restrict__ ea, const int* __restrict__ cidx,
                        const int* __restrict__ row_ptr, int N,
                        float* __restrict__ easum) {
    const int t = blockIdx.x * blockDim.x + threadIdx.x;
    const int w = t >> 5;
    const int lane = threadIdx.x & 31;
    if (w >= N) return;
    const int beg = row_ptr[w], end = row_ptr[w + 1];
    float s = 0.f;
    for (int i = beg; i < end; ++i) {
        int e = cidx[i];
        s += ea[(size_t)e * 32 + lane];
    }
    easum[(size_t)w * 32 + lane] = s;
}

// ---- MFMA GEMM: {xl,xr}[n][col] = in[n][:128] . W{l,r}[:, col] + b ---------
// Block: 64 nodes x 64 cols, both mats. Wave w owns nodes [w*16, w*16+16).
// A-frag (kc preloaded x4): in[node = m0+w*16+(l&15)][k = kc*32+(l>>4)*8+j].
// B-frag: Wsb[col = cg*16+(l&15)][kc*32+lk*8] (bf16 LDS, col-major rows).
// D (R13-verified): lane holds col = cg*16+(l&15)?? NO -> col=(l&15) is B col,
//   rows = 4 nodes (l>>4)*4+r. Store: 16 lanes consecutive cols = 32B/row.
template <int HC>
__global__ __launch_bounds__(256, 2) void k_xw(
        const float* __restrict__ in, int N,
        const float* __restrict__ Wl, const float* __restrict__ bl,
        const float* __restrict__ Wr, const float* __restrict__ br,
        unsigned short* __restrict__ outl, unsigned short* __restrict__ outr) {
    __shared__ __align__(16) unsigned short Wsb[64][136];  // [c][k], +8 pad
    const int tid = threadIdx.x;
    const int m0 = blockIdx.x * 64;
    const int cc0 = blockIdx.y * 64;

    const int lane = tid & 63;
    const int w = tid >> 6;
    const int lm = lane & 15;
    const int lk = lane >> 4;

    // A fragments: this lane's node row, 4 K-chunks of 32 (bf16)
    int node_in = m0 + w * 16 + lm;
    if (node_in >= N) node_in = N - 1;
    short8v afrag[4];
#pragma unroll
    for (int kc = 0; kc < 4; ++kc) {
        const float4* ap = (const float4*)(in + (size_t)node_in * 128 + kc * 32 + lk * 8);
        float4 v0 = ap[0], v1 = ap[1];
        afrag[kc][0] = (short)f2bf(v0.x); afrag[kc][1] = (short)f2bf(v0.y);
        afrag[kc][2] = (short)f2bf(v0.z); afrag[kc][3] = (short)f2bf(v0.w);
        afrag[kc][4] = (short)f2bf(v1.x); afrag[kc][5] = (short)f2bf(v1.y);
        afrag[kc][6] = (short)f2bf(v1.z); afrag[kc][7] = (short)f2bf(v1.w);
    }

#pragma unroll
    for (int mat = 0; mat < 2; ++mat) {
        const float* W = mat ? Wr : Wl;
        const float* b = mat ? br : bl;
        unsigned short* out = mat ? outr : outl;
        __syncthreads();  // prev-mat reads done before restaging
        // stage W cols cc0..cc0+63 as bf16 col-major: Wsb[c][k]
        for (int i4 = tid; i4 < 128 * 16; i4 += 256) {
            int k = i4 >> 4, c4 = i4 & 15;
            float4 v = *(const float4*)&W[(size_t)k * HC + cc0 + c4 * 4];
            Wsb[c4 * 4 + 0][k] = f2bf(v.x);
            Wsb[c4 * 4 + 1][k] = f2bf(v.y);
            Wsb[c4 * 4 + 2][k] = f2bf(v.z);
            Wsb[c4 * 4 + 3][k] = f2bf(v.w);
        }
        __syncthreads();

#pragma unroll
        for (int cg = 0; cg < 4; ++cg) {
            f32x4 acc = {0.f, 0.f, 0.f, 0.f};
#pragma unroll
            for (int kc = 0; kc < 4; ++kc) {
                short8v bfrag = *(const short8v*)&Wsb[cg * 16 + lm][kc * 32 + lk * 8];
                acc = __builtin_amdgcn_mfma_f32_16x16x32_bf16(afrag[kc], bfrag, acc, 0, 0, 0);
            }
            const int col = cc0 + cg * 16 + lm;   // this lane's D column
            const float bb = b[col];
#pragma unroll
            for (int r = 0; r < 4; ++r) {
                int n = m0 + w * 16 + lk * 4 + r;  // this lane's 4 D rows
                if (n < N) out[(size_t)n * HC + col] = f2bf(acc[r] + bb);
            }
        }
    }
}

// ---- EE GEMM (self-loop path): out[m][col] = A[m][:32] . We[:, col] --------
template <int HC>
__global__ __launch_bounds__(256, 2) void k_ee(
        const float* __restrict__ A, int M,
        const float* __restrict__ We,
        float* __restrict__ out) {
    __shared__ float As[32][68];
    __shared__ float Ws[32][64];
    const int tid = threadIdx.x;
    const int m0 = blockIdx.x * 64;
    const int cc = blockIdx.y;

#pragma unroll
    for (int t = 0; t < 2; ++t) {
        int idx4 = tid + t * 256;
        int r = idx4 >> 3, q = idx4 & 7;
        int n = m0 + r;
        float4 v = make_float4(0.f, 0.f, 0.f, 0.f);
        if (n < M) v = ((const float4*)A)[(size_t)n * 8 + q];
        As[q * 4 + 0][r] = v.x;
        As[q * 4 + 1][r] = v.y;
        As[q * 4 + 2][r] = v.z;
        As[q * 4 + 3][r] = v.w;
    }
#pragma unroll
    for (int i = tid; i < 32 * 64; i += 256) {
        int k = i >> 6, c = i & 63;
        Ws[k][c] = We[(size_t)k * HC + cc * 64 + c];
    }
    __syncthreads();

    const int rm = tid >> 4, rn = tid & 15;
    float acc[4][4];
#pragma unroll
    for (int i = 0; i < 4; ++i)
#pragma unroll
        for (int j = 0; j < 4; ++j) acc[i][j] = 0.f;
#pragma unroll
    for (int k = 0; k < 32; ++k) {
        float4 a = *(const float4*)&As[k][rm * 4];
        float4 bv = *(const float4*)&Ws[k][rn * 4];
        acc[0][0] += a.x * bv.x; acc[0][1] += a.x * bv.y;
        acc[0][2] += a.x * bv.z; acc[0][3] += a.x * bv.w;
        acc[1][0] += a.y * bv.x; acc[1][1] += a.y * bv.y;
        acc[1][2] += a.y * bv.z; acc[1][3] += a.y * bv.w;
        acc[2][0] += a.z * bv.x; acc[2][1] += a.z * bv.y;
        acc[2][2] += a.z * bv.z; acc[2][3] += a.z * bv.w;
        acc[3][0] += a.w * bv.x; acc[3][1] += a.w * bv.y;
        acc[3][2] += a.w * bv.z; acc[3][3] += a.w * bv.w;
    }
#pragma unroll
    for (int i = 0; i < 4; ++i) {
        int n = m0 + rm * 4 + i;
        if (n < M) {
            float4 o = make_float4(acc[i][0], acc[i][1], acc[i][2], acc[i][3]);
            *(float4*)&out[(size_t)n * HC + cc * 64 + rn * 4] = o;
        }
    }
}

// ---- fused edge logits in CSR order, MFMA (R13-validated, 136us) -----------
// 64 edges/block, 4 waves; wave w owns edges [w*16, w*16+16).
// A-frag: lane holds ea[edge = w*16 + (l&15)][k = (l>>4)*8 + j] (bf16).
// B-frag: Wsb[col][k0..k0+7] (transposed bf16 LDS tile, one ds_read_b128).
// D: lane holds 4 edges (row=(l>>4)*4+r) x 1 col (l&15) -> column-coalesced
// xl/xr gathers (16 lm-lanes read consecutive cols of the same edge row).
template <int H>
__global__ __launch_bounds__(256, 2) void k_fused(
        const unsigned short* __restrict__ xlb, const unsigned short* __restrict__ xrb,
        const float* __restrict__ ea,
        const int* __restrict__ cidx, const int* __restrict__ s_csr,
        const int* __restrict__ d_csr, int E,
        const float* __restrict__ We, const float* __restrict__ att,
        float* __restrict__ alpha) {
    constexpr int HC = H * 64;
    __shared__ __align__(16) unsigned short Wsb[HC][40];  // [col][k], 80B rows
    __shared__ int Es[64], Ss[64], Ds[64];
    const int tid = threadIdx.x;
    const int wg = xcd_swizzle(blockIdx.x, gridDim.x);
    const int i0 = wg * 64;

    if (tid < 64) {
        int i = i0 + tid;
        bool ok = i < E;
        Es[tid] = ok ? cidx[i] : 0;
        Ss[tid] = ok ? s_csr[i] : 0;
        Ds[tid] = ok ? d_csr[i] : 0;
    }
    // stage We transposed to bf16: Wsb[c][k]
    for (int idx4 = tid; idx4 < 32 * (HC / 4); idx4 += 256) {
        int k = idx4 / (HC / 4), c4 = idx4 % (HC / 4);
        float4 v = ((const float4*)We)[idx4];
        Wsb[c4 * 4 + 0][k] = f2bf(v.x);
        Wsb[c4 * 4 + 1][k] = f2bf(v.y);
        Wsb[c4 * 4 + 2][k] = f2bf(v.z);
        Wsb[c4 * 4 + 3][k] = f2bf(v.w);
    }
    __syncthreads();

    const int lane = tid & 63;
    const int w = tid >> 6;
    const int lm = lane & 15;   // A row (edge) / B,D col
    const int lk = lane >> 4;   // k-chunk / D row-group
    const int k0 = lk * 8;

    // A fragment: this wave's 16 edges x K=32 (bf16)
    short8v afrag;
    {
        int eidx = Es[w * 16 + lm];
        const float4* ap = (const float4*)(ea + (size_t)eidx * 32 + k0);
        float4 v0 = ap[0], v1 = ap[1];
        afrag[0] = (short)f2bf(v0.x); afrag[1] = (short)f2bf(v0.y);
        afrag[2] = (short)f2bf(v0.z); afrag[3] = (short)f2bf(v0.w);
        afrag[4] = (short)f2bf(v1.x); afrag[5] = (short)f2bf(v1.y);
        afrag[6] = (short)f2bf(v1.z); afrag[7] = (short)f2bf(v1.w);
    }
    // the 4 edges this lane consumes from D (rows lk*4+r)
    int sN[4], dN[4], gOk[4];
#pragma unroll
    for (int r = 0; r < 4; ++r) {
        int el = w * 16 + lk * 4 + r;
        sN[r] = Ss[el];
        dN[r] = Ds[el];
        gOk[r] = (i0 + el) < E;
    }

#pragma unroll
    for (int cc = 0; cc < H; ++cc) {
        float part[4] = {0.f, 0.f, 0.f, 0.f};
#pragma unroll
        for (int cg = 0; cg < 4; ++cg) {
            const int col = cc * 64 + cg * 16 + lm;
            short8v bfrag = *(const short8v*)&Wsb[col][k0];
            f32x4 dacc = {0.f, 0.f, 0.f, 0.f};
            dacc = __builtin_amdgcn_mfma_f32_16x16x32_bf16(afrag, bfrag, dacc, 0, 0, 0);
            float attv = att[col];
#pragma unroll
            for (int r = 0; r < 4; ++r) {
                float xa = bf2f(xlb[(size_t)sN[r] * HC + col]);
                float xb = bf2f(xrb[(size_t)dN[r] * HC + col]);
                float mv = xa + xb + dacc[r];
                mv = mv > 0.f ? mv : 0.2f * mv;
                part[r] += mv * attv;
            }
        }
        // reduce over the 16 cols held by this lane-group
#pragma unroll
        for (int off = 1; off < 16; off <<= 1)
#pragma unroll
            for (int r = 0; r < 4; ++r) part[r] += __shfl_xor(part[r], off);
        if (lm == 0) {
#pragma unroll
            for (int r = 0; r < 4; ++r) {
                if (gOk[r]) {
                    int gi = i0 + w * 16 + lk * 4 + r;
                    alpha[(size_t)gi * H + cc] = part[r];
                }
            }
        }
    }
}

// online-softmax aggregate over CSR segment, self-logit computed inline.
// One wave per node, lane = channel, 4-edge unroll; xl/xr gathered as bf16.
template <int H, bool RELU>
__global__ __launch_bounds__(256, 2) void k_aggr(
        const unsigned short* __restrict__ xlb, const unsigned short* __restrict__ xrb,
        const float* __restrict__ EEself, const int* __restrict__ deg,
        const float* __restrict__ att,
        const int* __restrict__ s_csr, const int* __restrict__ row_ptr,
        const float* __restrict__ alpha,
        const float* __restrict__ bias, int Nn,
        float* __restrict__ out) {
    constexpr int HC = H * 64;
    const int lane = threadIdx.x & 63;
    const int wg = xcd_swizzle(blockIdx.x, gridDim.x);
    const int n = wg * 4 + ((int)threadIdx.x >> 6);
    if (n >= Nn) return;

    // ---- self-loop logit, seeds the online softmax ----
    float m[H], den[H], acc[H];
    {
        int dg = deg[n];
        float inv = 1.f / (float)(dg > 0 ? dg : 1);
        float al[H];
#pragma unroll
        for (int h = 0; h < H; ++h) {
            float xlv = bf2f(xlb[(size_t)n * HC + h * 64 + lane]);
            float v = xlv + bf2f(xrb[(size_t)n * HC + h * 64 + lane])
                    + EEself[(size_t)n * HC + h * 64 + lane] * inv;
            v = v > 0.f ? v : 0.2f * v;
            al[h] = v * att[h * 64 + lane];
            acc[h] = xlv;
        }
#pragma unroll
        for (int off = 1; off < 64; off <<= 1)
#pragma unroll
            for (int h = 0; h < H; ++h) al[h] += __shfl_xor(al[h], off);
#pragma unroll
        for (int h = 0; h < H; ++h) { m[h] = al[h]; den[h] = 1.f; }
    }

    const int beg = row_ptr[n], end = row_ptr[n + 1];
    int i = beg;
    for (; i + 3 < end; i += 4) {
        int s0 = s_csr[i], s1 = s_csr[i + 1], s2 = s_csr[i + 2], s3 = s_csr[i + 3];
        float a0[H], a1[H], a2[H], a3[H], xv0[H], xv1[H], xv2[H], xv3[H];
#pragma unroll
        for (int h = 0; h < H; ++h) {
            a0[h] = alpha[(size_t)i * H + h];
            a1[h] = alpha[(size_t)(i + 1) * H + h];
            a2[h] = alpha[(size_t)(i + 2) * H + h];
            a3[h] = alpha[(size_t)(i + 3) * H + h];
            xv0[h] = bf2f(xlb[(size_t)s0 * HC + h * 64 + lane]);
            xv1[h] = bf2f(xlb[(size_t)s1 * HC + h * 64 + lane]);
            xv2[h] = bf2f(xlb[(size_t)s2 * HC + h * 64 + lane]);
            xv3[h] = bf2f(xlb[(size_t)s3 * HC + h * 64 + lane]);
        }
#pragma unroll
        for (int h = 0; h < H; ++h) {
            float mx01 = fmaxf(a0[h], a1[h]);
            float mx23 = fmaxf(a2[h], a3[h]);
            float nm = fmaxf(m[h], fmaxf(mx01, mx23));
            float corr = __expf(m[h] - nm);
            float p0 = __expf(a0[h] - nm);
            float p1 = __expf(a1[h] - nm);
            float p2 = __expf(a2[h] - nm);
            float p3 = __expf(a3[h] - nm);
            den[h] = den[h] * corr + (p0 + p1) + (p2 + p3);
            acc[h] = acc[h] * corr + (p0 * xv0[h] + p1 * xv1[h])
                                   + (p2 * xv2[h] + p3 * xv3[h]);
            m[h] = nm;
        }
    }
    for (; i < end; ++i) {
        int s = s_csr[i];
#pragma unroll
        for (int h = 0; h < H; ++h) {
            float a = alpha[(size_t)i * H + h];
            float xv = bf2f(xlb[(size_t)s * HC + h * 64 + lane]);
            float nm = fmaxf(m[h], a);
            float corr = __expf(m[h] - nm);
            float p = __expf(a - nm);
            den[h] = den[h] * corr + p;
            acc[h] = acc[h] * corr + p * xv;
            m[h] = nm;
        }
    }
#pragma unroll
    for (int h = 0; h < H; ++h) {
        float r = acc[h] / den[h] + bias[h * 64 + lane];
        if (RELU) r = r > 0.f ? r : 0.01f * r;
        out[(size_t)n * HC + h * 64 + lane] = r;
    }
}

// global_add_pool over sorted batch
__global__ void k_pool(const float* __restrict__ h2, const int* __restrict__ batch,
                       int Nn, float* __restrict__ g) {
    const int c = threadIdx.x;  // 0..191
    const int n0 = blockIdx.x * 128;
    if (n0 >= Nn) return;
    const int n1 = (n0 + 128 < Nn) ? n0 + 128 : Nn;
    float s = 0.f;
    int cur = batch[n0];
    for (int n = n0; n < n1; ++n) {
        int b = batch[n];
        if (b != cur) {
            atomicAdd(&g[cur * 192 + c], s);
            s = 0.f;
            cur = b;
        }
        s += h2[(size_t)n * 192 + c];
    }
    atomicAdd(&g[cur * 192 + c], s);
}

__global__ void k_mlp(const float* __restrict__ g,
                      const float* W1, const float* c1, const float* W2, const float* c2,
                      const float* W3, const float* c3, const float* W4, const float* c4,
                      const float* W5, const float* c5, const float* W6, const float* c6,
                      float* __restrict__ out) {
    __shared__ float t0[8 * 192];
    __shared__ float t1[8 * 64];
    __shared__ float t2[8 * 32];
    __shared__ float t3[8 * 16];
    __shared__ float t4[8 * 8];
    const int tid = threadIdx.x;
    for (int i = tid; i < 8 * 192; i += 256) t0[i] = g[i];
    __syncthreads();
    for (int i = tid; i < 8 * 64; i += 256) {
        int r = i >> 6, c = i & 63;
        float s = c1[c];
        for (int k = 0; k < 192; ++k) s += t0[r * 192 + k] * W1[k * 64 + c];
        t1[i] = s > 0.f ? s : 0.01f * s;
    }
    __syncthreads();
    for (int i = tid; i < 8 * 32; i += 256) {
        int r = i >> 5, c = i & 31;
        float s = c2[c];
        for (int k = 0; k < 64; ++k) s += t1[r * 64 + k] * W2[k * 32 + c];
        t2[i] = s > 0.f ? s : 0.01f * s;
    }
    __syncthreads();
    for (int i = tid; i < 8 * 16; i += 256) {
        int r = i >> 4, c = i & 15;
        float s = c3[c];
        for (int k = 0; k < 32; ++k) s += t2[r * 32 + k] * W3[k * 16 + c];
        t3[i] = s > 0.f ? s : 0.01f * s;
    }
    __syncthreads();
    for (int i = tid; i < 8 * 8; i += 256) {
        int r = i >> 3, c = i & 7;
        float s = c4[c];
        for (int k = 0; k < 16; ++k) s += t3[r * 16 + k] * W4[k * 8 + c];
        t4[i] = s > 0.f ? s : 0.01f * s;
    }
    __syncthreads();
    if (tid < 8) {
        float s = c5[0];
        for (int k = 0; k < 8; ++k) s += t4[tid * 8 + k] * W5[k];
        s = s * W6[0] + c6[0];
        out[tid] = s;
    }
}

extern "C" void kernel_launch(void* const* d_in, const int* in_sizes, int n_in,
                              void* d_out, int out_size, void* d_ws, size_t ws_size,
                              hipStream_t stream) {
    const float* x     = (const float*)d_in[0];
    const int*   eidx  = (const int*)d_in[1];
    const float* ea    = (const float*)d_in[2];
    const int*   batch = (const int*)d_in[3];
    const float* Wl1 = (const float*)d_in[4];
    const float* bl1 = (const float*)d_in[5];
    const float* Wr1 = (const float*)d_in[6];
    const float* br1 = (const float*)d_in[7];
    const float* We1 = (const float*)d_in[8];
    const float* att1 = (const float*)d_in[9];
    const float* bias1 = (const float*)d_in[10];
    const float* Wl2 = (const float*)d_in[11];
    const float* bl2 = (const float*)d_in[12];
    const float* Wr2 = (const float*)d_in[13];
    const float* br2 = (const float*)d_in[14];
    const float* We2 = (const float*)d_in[15];
    const float* att2 = (const float*)d_in[16];
    const float* bias2 = (const float*)d_in[17];
    const float* W1 = (const float*)d_in[18];
    const float* c1 = (const float*)d_in[19];
    const float* W2 = (const float*)d_in[20];
    const float* c2 = (const float*)d_in[21];
    const float* W3 = (const float*)d_in[22];
    const float* c3 = (const float*)d_in[23];
    const float* W4 = (const float*)d_in[24];
    const float* c4 = (const float*)d_in[25];
    const float* W5 = (const float*)d_in[26];
    const float* c5 = (const float*)d_in[27];
    const float* W6 = (const float*)d_in[28];
    const float* c6 = (const float*)d_in[29];

    const int N = in_sizes[0] / 128;
    const int E = in_sizes[1] / 2;
    const int* srcs = eidx;
    const int* dsts = eidx + E;

    char* p = (char*)d_ws;
    auto alloc = [&](size_t bytes) -> char* {
        char* r = p;
        p += (bytes + 255) & ~(size_t)255;
        return r;
    };
    int*            deg     = (int*)alloc((size_t)N * 4);
    int*            row_ptr = (int*)alloc((size_t)(N + 1) * 4);
    int*            woff    = (int*)alloc((size_t)N * 4);
    int*            cidx    = (int*)alloc((size_t)E * 4);
    int*            s_csr   = (int*)alloc((size_t)E * 4);
    int*            d_csr   = (int*)alloc((size_t)E * 4);
    int*            incl    = (int*)alloc((size_t)N * 4);
    int*            bsum    = (int*)alloc(64 * 4);
    float*          easum   = (float*)alloc((size_t)N * 32 * 4);
    float*          EEself  = (float*)alloc((size_t)N * 192 * 4);
    unsigned short* xlb     = (unsigned short*)alloc((size_t)N * 192 * 2);
    unsigned short* xrb     = (unsigned short*)alloc((size_t)N * 192 * 2);
    float*          h1      = (float*)alloc((size_t)N * 128 * 4);
    float*          h2      = (float*)alloc((size_t)N * 192 * 4);
    float*          alpha   = (float*)alloc((size_t)E * 3 * 4);
    float*          gp      = (float*)alloc(8 * 192 * 4);

    hipMemsetAsync(deg, 0, (size_t)N * 4, stream);
    hipMemsetAsync(gp, 0, 8 * 192 * 4, stream);

    // CSR build
    const int nb = (N + 2047) / 2048;
    k_deg<<<(E + 255) / 256, 256, 0, stream>>>(dsts, E, deg);
    k_scan1<<<nb, 256, 0, stream>>>(deg, N, incl, bsum);
    k_scan2<<<1, 64, 0, stream>>>(bsum, nb);
    k_scan3<<<(N + 255) / 256, 256, 0, stream>>>(incl, deg, bsum, N, row_ptr, woff);
    k_scatter<<<(E + 255) / 256, 256, 0, stream>>>(srcs, dsts, E, woff, cidx, s_csr, d_csr);

    const int mt = (N + 63) / 64;   // GEMM row tiles
    const int et = (E + 63) / 64;   // fused edge tiles (64 edges/block)
    const int nblk = (N + 3) / 4;   // node-parallel blocks (1 wave/node)

    k_easeg<<<(N * 32 + 255) / 256, 256, 0, stream>>>(ea, cidx, row_ptr, N, easum);

    // ---------------- conv1: H=2, HC=128 ----------------
    k_xw<128><<<dim3(mt, 2), 256, 0, stream>>>(x, N, Wl1, bl1, Wr1, br1, xlb, xrb);
    k_ee<128><<<dim3(mt, 2), 256, 0, stream>>>(easum, N, We1, EEself);
    k_fused<2><<<et, 256, 0, stream>>>(xlb, xrb, ea, cidx, s_csr, d_csr, E, We1, att1, alpha);
    k_aggr<2, true><<<nblk, 256, 0, stream>>>(xlb, xrb, EEself, deg, att1, s_csr, row_ptr,
                                              alpha, bias1, N, h1);

    // ---------------- conv2: H=3, HC=192 ----------------
    k_xw<192><<<dim3(mt, 3), 256, 0, stream>>>(h1, N, Wl2, bl2, Wr2, br2, xlb, xrb);
    k_ee<192><<<dim3(mt, 3), 256, 0, stream>>>(easum, N, We2, EEself);
    k_fused<3><<<et, 256, 0, stream>>>(xlb, xrb, ea, cidx, s_csr, d_csr, E, We2, att2, alpha);
    k_aggr<3, true><<<nblk, 256, 0, stream>>>(xlb, xrb, EEself, deg, att2, s_csr, row_ptr,
                                              alpha, bias2, N, h2);

    k_pool<<<(N + 127) / 128, 192, 0, stream>>>(h2, batch, N, gp);
    k_mlp<<<1, 256, 0, stream>>>(gp, W1, c1, W2, c2, W3, c3, W4, c4, W5, c5, W6, c6,
                                 (float*)d_out);
}

// Round 18
// 703.598 us; speedup vs baseline: 1.1834x; 1.0153x over previous
//
#include <hip/hip_runtime.h>
#include <hip/hip_bf16.h>
#include <math.h>

// ---------------------------------------------------------------------------
// GATv2 x2 + global_add_pool + MLP head.
// xl/xr/h1 as bf16 mirrors. k_fused: R13-validated MFMA edge kernel (A=ea
// edges, B=We cols in LDS, D = 1 col x 4 edges -> column-coalesced gathers).
// k_xw: MFMA GEMM (bf16 A-frags loaded directly when input is bf16).
// Self-logit folded into online-softmax aggregation (k_aggr, (256,3)).
// Machine model (R8-R10): waves/SIMD = 256/VGPR; never force 4 waves/EU on
// fat kernels. k_fused bank conflicts are latency-hidden (R16 proof).
// ---------------------------------------------------------------------------

typedef __attribute__((ext_vector_type(8))) short short8v;
typedef __attribute__((ext_vector_type(4))) float f32x4;

__device__ __forceinline__ unsigned short f2bf(float f) {
    union { float f; unsigned u; } v; v.f = f;
    unsigned r = v.u + 0x7fff + ((v.u >> 16) & 1);
    return (unsigned short)(r >> 16);
}
__device__ __forceinline__ float bf2f(unsigned short b) {
    union { unsigned u; float f; } v; v.u = ((unsigned)b) << 16;
    return v.f;
}

__device__ __forceinline__ int xcd_swizzle(int bid, int nwg) {
    int sq = nwg >> 3, sr = nwg & 7;
    int xcd = bid & 7, idx = bid >> 3;
    return (xcd < sr ? xcd * (sq + 1) : sr * (sq + 1) + (xcd - sr) * sq) + idx;
}

__global__ void k_deg(const int* __restrict__ dst, int E, int* __restrict__ deg) {
    int e = blockIdx.x * blockDim.x + threadIdx.x;
    if (e < E) atomicAdd(&deg[dst[e]], 1);
}

// ---- multi-block exclusive scan: deg[N] -> row_ptr[N+1], woff[N] ----------
__global__ void k_scan1(const int* __restrict__ deg, int N,
                        int* __restrict__ incl, int* __restrict__ bsum) {
    __shared__ int ws4[4];
    const int tid = threadIdx.x;
    const int lane = tid & 63, w = tid >> 6;
    const int base = blockIdx.x * 2048;
    int v[8];
    int s = 0;
#pragma unroll
    for (int j = 0; j < 8; ++j) {
        int i = base + tid * 8 + j;
        v[j] = (i < N) ? deg[i] : 0;
        s += v[j];
    }
    int ps = s;
#pragma unroll
    for (int off = 1; off < 64; off <<= 1) {
        int t = __shfl_up(ps, off);
        if (lane >= off) ps += t;
    }
    if (lane == 63) ws4[w] = ps;
    __syncthreads();
    int woffs = 0;
#pragma unroll
    for (int k = 0; k < 4; ++k)
        if (k < w) woffs += ws4[k];
    int run = ps - s + woffs;
#pragma unroll
    for (int j = 0; j < 8; ++j) {
        run += v[j];
        int i = base + tid * 8 + j;
        if (i < N) incl[i] = run;
    }
    if (tid == 255) bsum[blockIdx.x] = run;
}

__global__ void k_scan2(int* __restrict__ bsum, int nb) {
    if (threadIdx.x == 0) {
        int c = 0;
        for (int k = 0; k < nb; ++k) { int t = bsum[k]; bsum[k] = c; c += t; }
    }
}

__global__ void k_scan3(const int* __restrict__ incl, const int* __restrict__ deg,
                        const int* __restrict__ boff, int N,
                        int* __restrict__ row_ptr, int* __restrict__ woff) {
    int i = blockIdx.x * blockDim.x + threadIdx.x;
    if (i < N) {
        int v = incl[i] + boff[i >> 11];
        row_ptr[i + 1] = v;
        woff[i] = v - deg[i];
        if (i == 0) row_ptr[0] = 0;
    }
}

// scatter edges into CSR order; also materialize src/dst in CSR order
__global__ void k_scatter(const int* __restrict__ src, const int* __restrict__ dst,
                          int E, int* __restrict__ woff, int* __restrict__ cidx,
                          int* __restrict__ s_csr, int* __restrict__ d_csr) {
    int e = blockIdx.x * blockDim.x + threadIdx.x;
    if (e < E) {
        int d = dst[e];
        int p = atomicAdd(&woff[d], 1);
        cidx[p] = e;
        s_csr[p] = src[e];
        d_csr[p] = d;
    }
}

// segmented sum of edge attrs per dst (CSR order): 32-lane group per node
__global__ void k_easeg(const float* __restrict__ ea, const int* __restrict__ cidx,
                        const int* __restrict__ row_ptr, int N,
                        float* __restrict__ easum) {
    const int t = blockIdx.x * blockDim.x + threadIdx.x;
    const int w = t >> 5;
    const int lane = threadIdx.x & 31;
    if (w >= N) return;
    const int beg = row_ptr[w], end = row_ptr[w + 1];
    float s = 0.f;
    for (int i = beg; i < end; ++i) {
        int e = cidx[i];
        s += ea[(size_t)e * 32 + lane];
    }
    easum[(size_t)w * 32 + lane] = s;
}

// ---- MFMA GEMM: {xl,xr}[n][col] = in[n][:128] . W{l,r}[:, col] + b ---------
// Block: 64 nodes x 64 cols, both mats. Wave w owns nodes [w*16, w*16+16).
// INBF: input is bf16 (h1 mirror) -> A-frag is a direct 16B vector load.
template <int HC, bool INBF>
__global__ __launch_bounds__(256, 2) void k_xw(
        const void* __restrict__ in_, int N,
        const float* __restrict__ Wl, const float* __restrict__ bl,
        const float* __restrict__ Wr, const float* __restrict__ br,
        unsigned short* __restrict__ outl, unsigned short* __restrict__ outr) {
    __shared__ __align__(16) unsigned short Wsb[64][136];  // [c][k], +8 pad
    const int tid = threadIdx.x;
    const int m0 = blockIdx.x * 64;
    const int cc0 = blockIdx.y * 64;

    const int lane = tid & 63;
    const int w = tid >> 6;
    const int lm = lane & 15;
    const int lk = lane >> 4;

    // A fragments: this lane's node row, 4 K-chunks of 32 (bf16)
    int node_in = m0 + w * 16 + lm;
    if (node_in >= N) node_in = N - 1;
    short8v afrag[4];
#pragma unroll
    for (int kc = 0; kc < 4; ++kc) {
        if constexpr (INBF) {
            const unsigned short* in = (const unsigned short*)in_;
            afrag[kc] = *(const short8v*)&in[(size_t)node_in * 128 + kc * 32 + lk * 8];
        } else {
            const float* in = (const float*)in_;
            const float4* ap = (const float4*)(in + (size_t)node_in * 128 + kc * 32 + lk * 8);
            float4 v0 = ap[0], v1 = ap[1];
            afrag[kc][0] = (short)f2bf(v0.x); afrag[kc][1] = (short)f2bf(v0.y);
            afrag[kc][2] = (short)f2bf(v0.z); afrag[kc][3] = (short)f2bf(v0.w);
            afrag[kc][4] = (short)f2bf(v1.x); afrag[kc][5] = (short)f2bf(v1.y);
            afrag[kc][6] = (short)f2bf(v1.z); afrag[kc][7] = (short)f2bf(v1.w);
        }
    }

#pragma unroll
    for (int mat = 0; mat < 2; ++mat) {
        const float* W = mat ? Wr : Wl;
        const float* b = mat ? br : bl;
        unsigned short* out = mat ? outr : outl;
        __syncthreads();  // prev-mat reads done before restaging
        // stage W cols cc0..cc0+63 as bf16 col-major: Wsb[c][k]
        for (int i4 = tid; i4 < 128 * 16; i4 += 256) {
            int k = i4 >> 4, c4 = i4 & 15;
            float4 v = *(const float4*)&W[(size_t)k * HC + cc0 + c4 * 4];
            Wsb[c4 * 4 + 0][k] = f2bf(v.x);
            Wsb[c4 * 4 + 1][k] = f2bf(v.y);
            Wsb[c4 * 4 + 2][k] = f2bf(v.z);
            Wsb[c4 * 4 + 3][k] = f2bf(v.w);
        }
        __syncthreads();

#pragma unroll
        for (int cg = 0; cg < 4; ++cg) {
            f32x4 acc = {0.f, 0.f, 0.f, 0.f};
#pragma unroll
            for (int kc = 0; kc < 4; ++kc) {
                short8v bfrag = *(const short8v*)&Wsb[cg * 16 + lm][kc * 32 + lk * 8];
                acc = __builtin_amdgcn_mfma_f32_16x16x32_bf16(afrag[kc], bfrag, acc, 0, 0, 0);
            }
            const int col = cc0 + cg * 16 + lm;   // this lane's D column
            const float bb = b[col];
#pragma unroll
            for (int r = 0; r < 4; ++r) {
                int n = m0 + w * 16 + lk * 4 + r;  // this lane's 4 D rows
                if (n < N) out[(size_t)n * HC + col] = f2bf(acc[r] + bb);
            }
        }
    }
}

// ---- EE GEMM (self-loop path): out[m][col] = A[m][:32] . We[:, col] --------
template <int HC>
__global__ __launch_bounds__(256, 2) void k_ee(
        const float* __restrict__ A, int M,
        const float* __restrict__ We,
        float* __restrict__ out) {
    __shared__ float As[32][68];
    __shared__ float Ws[32][64];
    const int tid = threadIdx.x;
    const int m0 = blockIdx.x * 64;
    const int cc = blockIdx.y;

#pragma unroll
    for (int t = 0; t < 2; ++t) {
        int idx4 = tid + t * 256;
        int r = idx4 >> 3, q = idx4 & 7;
        int n = m0 + r;
        float4 v = make_float4(0.f, 0.f, 0.f, 0.f);
        if (n < M) v = ((const float4*)A)[(size_t)n * 8 + q];
        As[q * 4 + 0][r] = v.x;
        As[q * 4 + 1][r] = v.y;
        As[q * 4 + 2][r] = v.z;
        As[q * 4 + 3][r] = v.w;
    }
#pragma unroll
    for (int i = tid; i < 32 * 64; i += 256) {
        int k = i >> 6, c = i & 63;
        Ws[k][c] = We[(size_t)k * HC + cc * 64 + c];
    }
    __syncthreads();

    const int rm = tid >> 4, rn = tid & 15;
    float acc[4][4];
#pragma unroll
    for (int i = 0; i < 4; ++i)
#pragma unroll
        for (int j = 0; j < 4; ++j) acc[i][j] = 0.f;
#pragma unroll
    for (int k = 0; k < 32; ++k) {
        float4 a = *(const float4*)&As[k][rm * 4];
        float4 bv = *(const float4*)&Ws[k][rn * 4];
        acc[0][0] += a.x * bv.x; acc[0][1] += a.x * bv.y;
        acc[0][2] += a.x * bv.z; acc[0][3] += a.x * bv.w;
        acc[1][0] += a.y * bv.x; acc[1][1] += a.y * bv.y;
        acc[1][2] += a.y * bv.z; acc[1][3] += a.y * bv.w;
        acc[2][0] += a.z * bv.x; acc[2][1] += a.z * bv.y;
        acc[2][2] += a.z * bv.z; acc[2][3] += a.z * bv.w;
        acc[3][0] += a.w * bv.x; acc[3][1] += a.w * bv.y;
        acc[3][2] += a.w * bv.z; acc[3][3] += a.w * bv.w;
    }
#pragma unroll
    for (int i = 0; i < 4; ++i) {
        int n = m0 + rm * 4 + i;
        if (n < M) {
            float4 o = make_float4(acc[i][0], acc[i][1], acc[i][2], acc[i][3]);
            *(float4*)&out[(size_t)n * HC + cc * 64 + rn * 4] = o;
        }
    }
}

// ---- fused edge logits in CSR order, MFMA (R13-validated) ------------------
// 64 edges/block, 4 waves; wave w owns edges [w*16, w*16+16).
// A-frag: lane holds ea[edge = w*16 + (l&15)][k = (l>>4)*8 + j] (bf16).
// B-frag: Wsb[col][k0..k0+7] (transposed bf16 LDS tile, one ds_read_b128).
// D: lane holds 4 edges (row=(l>>4)*4+r) x 1 col (l&15) -> column-coalesced
// xl/xr gathers (16 lm-lanes read consecutive cols of the same edge row).
template <int H>
__global__ __launch_bounds__(256, 2) void k_fused(
        const unsigned short* __restrict__ xlb, const unsigned short* __restrict__ xrb,
        const float* __restrict__ ea,
        const int* __restrict__ cidx, const int* __restrict__ s_csr,
        const int* __restrict__ d_csr, int E,
        const float* __restrict__ We, const float* __restrict__ att,
        float* __restrict__ alpha) {
    constexpr int HC = H * 64;
    __shared__ __align__(16) unsigned short Wsb[HC][40];  // [col][k], 80B rows
    __shared__ int Es[64], Ss[64], Ds[64];
    const int tid = threadIdx.x;
    const int wg = xcd_swizzle(blockIdx.x, gridDim.x);
    const int i0 = wg * 64;

    if (tid < 64) {
        int i = i0 + tid;
        bool ok = i < E;
        Es[tid] = ok ? cidx[i] : 0;
        Ss[tid] = ok ? s_csr[i] : 0;
        Ds[tid] = ok ? d_csr[i] : 0;
    }
    // stage We transposed to bf16: Wsb[c][k]
    for (int idx4 = tid; idx4 < 32 * (HC / 4); idx4 += 256) {
        int k = idx4 / (HC / 4), c4 = idx4 % (HC / 4);
        float4 v = ((const float4*)We)[idx4];
        Wsb[c4 * 4 + 0][k] = f2bf(v.x);
        Wsb[c4 * 4 + 1][k] = f2bf(v.y);
        Wsb[c4 * 4 + 2][k] = f2bf(v.z);
        Wsb[c4 * 4 + 3][k] = f2bf(v.w);
    }
    __syncthreads();

    const int lane = tid & 63;
    const int w = tid >> 6;
    const int lm = lane & 15;   // A row (edge) / B,D col
    const int lk = lane >> 4;   // k-chunk / D row-group
    const int k0 = lk * 8;

    // A fragment: this wave's 16 edges x K=32 (bf16)
    short8v afrag;
    {
        int eidx = Es[w * 16 + lm];
        const float4* ap = (const float4*)(ea + (size_t)eidx * 32 + k0);
        float4 v0 = ap[0], v1 = ap[1];
        afrag[0] = (short)f2bf(v0.x); afrag[1] = (short)f2bf(v0.y);
        afrag[2] = (short)f2bf(v0.z); afrag[3] = (short)f2bf(v0.w);
        afrag[4] = (short)f2bf(v1.x); afrag[5] = (short)f2bf(v1.y);
        afrag[6] = (short)f2bf(v1.z); afrag[7] = (short)f2bf(v1.w);
    }
    // the 4 edges this lane consumes from D (rows lk*4+r)
    int sN[4], dN[4], gOk[4];
#pragma unroll
    for (int r = 0; r < 4; ++r) {
        int el = w * 16 + lk * 4 + r;
        sN[r] = Ss[el];
        dN[r] = Ds[el];
        gOk[r] = (i0 + el) < E;
    }

#pragma unroll
    for (int cc = 0; cc < H; ++cc) {
        float part[4] = {0.f, 0.f, 0.f, 0.f};
#pragma unroll
        for (int cg = 0; cg < 4; ++cg) {
            const int col = cc * 64 + cg * 16 + lm;
            short8v bfrag = *(const short8v*)&Wsb[col][k0];
            f32x4 dacc = {0.f, 0.f, 0.f, 0.f};
            dacc = __builtin_amdgcn_mfma_f32_16x16x32_bf16(afrag, bfrag, dacc, 0, 0, 0);
            float attv = att[col];
#pragma unroll
            for (int r = 0; r < 4; ++r) {
                float xa = bf2f(xlb[(size_t)sN[r] * HC + col]);
                float xb = bf2f(xrb[(size_t)dN[r] * HC + col]);
                float mv = xa + xb + dacc[r];
                mv = mv > 0.f ? mv : 0.2f * mv;
                part[r] += mv * attv;
            }
        }
        // reduce over the 16 cols held by this lane-group
#pragma unroll
        for (int off = 1; off < 16; off <<= 1)
#pragma unroll
            for (int r = 0; r < 4; ++r) part[r] += __shfl_xor(part[r], off);
        if (lm == 0) {
#pragma unroll
            for (int r = 0; r < 4; ++r) {
                if (gOk[r]) {
                    int gi = i0 + w * 16 + lk * 4 + r;
                    alpha[(size_t)gi * H + cc] = part[r];
                }
            }
        }
    }
}

// online-softmax aggregate over CSR segment, self-logit computed inline.
// One wave per node, lane = channel, 4-edge unroll; xl/xr gathered as bf16.
// OUTBF: store output as bf16 (h1 mirror for conv2's k_xw).
template <int H, bool RELU, bool OUTBF>
__global__ __launch_bounds__(256, 3) void k_aggr(
        const unsigned short* __restrict__ xlb, const unsigned short* __restrict__ xrb,
        const float* __restrict__ EEself, const int* __restrict__ deg,
        const float* __restrict__ att,
        const int* __restrict__ s_csr, const int* __restrict__ row_ptr,
        const float* __restrict__ alpha,
        const float* __restrict__ bias, int Nn,
        void* __restrict__ out_) {
    constexpr int HC = H * 64;
    const int lane = threadIdx.x & 63;
    const int wg = xcd_swizzle(blockIdx.x, gridDim.x);
    const int n = wg * 4 + ((int)threadIdx.x >> 6);
    if (n >= Nn) return;

    // ---- self-loop logit, seeds the online softmax ----
    float m[H], den[H], acc[H];
    {
        int dg = deg[n];
        float inv = 1.f / (float)(dg > 0 ? dg : 1);
        float al[H];
#pragma unroll
        for (int h = 0; h < H; ++h) {
            float xlv = bf2f(xlb[(size_t)n * HC + h * 64 + lane]);
            float v = xlv + bf2f(xrb[(size_t)n * HC + h * 64 + lane])
                    + EEself[(size_t)n * HC + h * 64 + lane] * inv;
            v = v > 0.f ? v : 0.2f * v;
            al[h] = v * att[h * 64 + lane];
            acc[h] = xlv;
        }
#pragma unroll
        for (int off = 1; off < 64; off <<= 1)
#pragma unroll
            for (int h = 0; h < H; ++h) al[h] += __shfl_xor(al[h], off);
#pragma unroll
        for (int h = 0; h < H; ++h) { m[h] = al[h]; den[h] = 1.f; }
    }

    const int beg = row_ptr[n], end = row_ptr[n + 1];
    int i = beg;
    for (; i + 3 < end; i += 4) {
        int s0 = s_csr[i], s1 = s_csr[i + 1], s2 = s_csr[i + 2], s3 = s_csr[i + 3];
        float a0[H], a1[H], a2[H], a3[H], xv0[H], xv1[H], xv2[H], xv3[H];
#pragma unroll
        for (int h = 0; h < H; ++h) {
            a0[h] = alpha[(size_t)i * H + h];
            a1[h] = alpha[(size_t)(i + 1) * H + h];
            a2[h] = alpha[(size_t)(i + 2) * H + h];
            a3[h] = alpha[(size_t)(i + 3) * H + h];
            xv0[h] = bf2f(xlb[(size_t)s0 * HC + h * 64 + lane]);
            xv1[h] = bf2f(xlb[(size_t)s1 * HC + h * 64 + lane]);
            xv2[h] = bf2f(xlb[(size_t)s2 * HC + h * 64 + lane]);
            xv3[h] = bf2f(xlb[(size_t)s3 * HC + h * 64 + lane]);
        }
#pragma unroll
        for (int h = 0; h < H; ++h) {
            float mx01 = fmaxf(a0[h], a1[h]);
            float mx23 = fmaxf(a2[h], a3[h]);
            float nm = fmaxf(m[h], fmaxf(mx01, mx23));
            float corr = __expf(m[h] - nm);
            float p0 = __expf(a0[h] - nm);
            float p1 = __expf(a1[h] - nm);
            float p2 = __expf(a2[h] - nm);
            float p3 = __expf(a3[h] - nm);
            den[h] = den[h] * corr + (p0 + p1) + (p2 + p3);
            acc[h] = acc[h] * corr + (p0 * xv0[h] + p1 * xv1[h])
                                   + (p2 * xv2[h] + p3 * xv3[h]);
            m[h] = nm;
        }
    }
    for (; i < end; ++i) {
        int s = s_csr[i];
#pragma unroll
        for (int h = 0; h < H; ++h) {
            float a = alpha[(size_t)i * H + h];
            float xv = bf2f(xlb[(size_t)s * HC + h * 64 + lane]);
            float nm = fmaxf(m[h], a);
            float corr = __expf(m[h] - nm);
            float p = __expf(a - nm);
            den[h] = den[h] * corr + p;
            acc[h] = acc[h] * corr + p * xv;
            m[h] = nm;
        }
    }
#pragma unroll
    for (int h = 0; h < H; ++h) {
        float r = acc[h] / den[h] + bias[h * 64 + lane];
        if (RELU) r = r > 0.f ? r : 0.01f * r;
        if constexpr (OUTBF)
            ((unsigned short*)out_)[(size_t)n * HC + h * 64 + lane] = f2bf(r);
        else
            ((float*)out_)[(size_t)n * HC + h * 64 + lane] = r;
    }
}

// global_add_pool over sorted batch
__global__ void k_pool(const float* __restrict__ h2, const int* __restrict__ batch,
                       int Nn, float* __restrict__ g) {
    const int c = threadIdx.x;  // 0..191
    const int n0 = blockIdx.x * 128;
    if (n0 >= Nn) return;
    const int n1 = (n0 + 128 < Nn) ? n0 + 128 : Nn;
    float s = 0.f;
    int cur = batch[n0];
    for (int n = n0; n < n1; ++n) {
        int b = batch[n];
        if (b != cur) {
            atomicAdd(&g[cur * 192 + c], s);
            s = 0.f;
            cur = b;
        }
        s += h2[(size_t)n * 192 + c];
    }
    atomicAdd(&g[cur * 192 + c], s);
}

__global__ void k_mlp(const float* __restrict__ g,
                      const float* W1, const float* c1, const float* W2, const float* c2,
                      const float* W3, const float* c3, const float* W4, const float* c4,
                      const float* W5, const float* c5, const float* W6, const float* c6,
                      float* __restrict__ out) {
    __shared__ float t0[8 * 192];
    __shared__ float t1[8 * 64];
    __shared__ float t2[8 * 32];
    __shared__ float t3[8 * 16];
    __shared__ float t4[8 * 8];
    const int tid = threadIdx.x;
    for (int i = tid; i < 8 * 192; i += 256) t0[i] = g[i];
    __syncthreads();
    for (int i = tid; i < 8 * 64; i += 256) {
        int r = i >> 6, c = i & 63;
        float s = c1[c];
        for (int k = 0; k < 192; ++k) s += t0[r * 192 + k] * W1[k * 64 + c];
        t1[i] = s > 0.f ? s : 0.01f * s;
    }
    __syncthreads();
    for (int i = tid; i < 8 * 32; i += 256) {
        int r = i >> 5, c = i & 31;
        float s = c2[c];
        for (int k = 0; k < 64; ++k) s += t1[r * 64 + k] * W2[k * 32 + c];
        t2[i] = s > 0.f ? s : 0.01f * s;
    }
    __syncthreads();
    for (int i = tid; i < 8 * 16; i += 256) {
        int r = i >> 4, c = i & 15;
        float s = c3[c];
        for (int k = 0; k < 32; ++k) s += t2[r * 32 + k] * W3[k * 16 + c];
        t3[i] = s > 0.f ? s : 0.01f * s;
    }
    __syncthreads();
    for (int i = tid; i < 8 * 8; i += 256) {
        int r = i >> 3, c = i & 7;
        float s = c4[c];
        for (int k = 0; k < 16; ++k) s += t3[r * 16 + k] * W4[k * 8 + c];
        t4[i] = s > 0.f ? s : 0.01f * s;
    }
    __syncthreads();
    if (tid < 8) {
        float s = c5[0];
        for (int k = 0; k < 8; ++k) s += t4[tid * 8 + k] * W5[k];
        s = s * W6[0] + c6[0];
        out[tid] = s;
    }
}

extern "C" void kernel_launch(void* const* d_in, const int* in_sizes, int n_in,
                              void* d_out, int out_size, void* d_ws, size_t ws_size,
                              hipStream_t stream) {
    const float* x     = (const float*)d_in[0];
    const int*   eidx  = (const int*)d_in[1];
    const float* ea    = (const float*)d_in[2];
    const int*   batch = (const int*)d_in[3];
    const float* Wl1 = (const float*)d_in[4];
    const float* bl1 = (const float*)d_in[5];
    const float* Wr1 = (const float*)d_in[6];
    const float* br1 = (const float*)d_in[7];
    const float* We1 = (const float*)d_in[8];
    const float* att1 = (const float*)d_in[9];
    const float* bias1 = (const float*)d_in[10];
    const float* Wl2 = (const float*)d_in[11];
    const float* bl2 = (const float*)d_in[12];
    const float* Wr2 = (const float*)d_in[13];
    const float* br2 = (const float*)d_in[14];
    const float* We2 = (const float*)d_in[15];
    const float* att2 = (const float*)d_in[16];
    const float* bias2 = (const float*)d_in[17];
    const float* W1 = (const float*)d_in[18];
    const float* c1 = (const float*)d_in[19];
    const float* W2 = (const float*)d_in[20];
    const float* c2 = (const float*)d_in[21];
    const float* W3 = (const float*)d_in[22];
    const float* c3 = (const float*)d_in[23];
    const float* W4 = (const float*)d_in[24];
    const float* c4 = (const float*)d_in[25];
    const float* W5 = (const float*)d_in[26];
    const float* c5 = (const float*)d_in[27];
    const float* W6 = (const float*)d_in[28];
    const float* c6 = (const float*)d_in[29];

    const int N = in_sizes[0] / 128;
    const int E = in_sizes[1] / 2;
    const int* srcs = eidx;
    const int* dsts = eidx + E;

    char* p = (char*)d_ws;
    auto alloc = [&](size_t bytes) -> char* {
        char* r = p;
        p += (bytes + 255) & ~(size_t)255;
        return r;
    };
    int*            deg     = (int*)alloc((size_t)N * 4);
    int*            row_ptr = (int*)alloc((size_t)(N + 1) * 4);
    int*            woff    = (int*)alloc((size_t)N * 4);
    int*            cidx    = (int*)alloc((size_t)E * 4);
    int*            s_csr   = (int*)alloc((size_t)E * 4);
    int*            d_csr   = (int*)alloc((size_t)E * 4);
    int*            incl    = (int*)alloc((size_t)N * 4);
    int*            bsum    = (int*)alloc(64 * 4);
    float*          easum   = (float*)alloc((size_t)N * 32 * 4);
    float*          EEself  = (float*)alloc((size_t)N * 192 * 4);
    unsigned short* xlb     = (unsigned short*)alloc((size_t)N * 192 * 2);
    unsigned short* xrb     = (unsigned short*)alloc((size_t)N * 192 * 2);
    unsigned short* h1b     = (unsigned short*)alloc((size_t)N * 128 * 2);
    float*          h2      = (float*)alloc((size_t)N * 192 * 4);
    float*          alpha   = (float*)alloc((size_t)E * 3 * 4);
    float*          gp      = (float*)alloc(8 * 192 * 4);

    hipMemsetAsync(deg, 0, (size_t)N * 4, stream);
    hipMemsetAsync(gp, 0, 8 * 192 * 4, stream);

    // CSR build
    const int nb = (N + 2047) / 2048;
    k_deg<<<(E + 255) / 256, 256, 0, stream>>>(dsts, E, deg);
    k_scan1<<<nb, 256, 0, stream>>>(deg, N, incl, bsum);
    k_scan2<<<1, 64, 0, stream>>>(bsum, nb);
    k_scan3<<<(N + 255) / 256, 256, 0, stream>>>(incl, deg, bsum, N, row_ptr, woff);
    k_scatter<<<(E + 255) / 256, 256, 0, stream>>>(srcs, dsts, E, woff, cidx, s_csr, d_csr);

    const int mt = (N + 63) / 64;   // GEMM row tiles
    const int et = (E + 63) / 64;   // fused edge tiles (64 edges/block)
    const int nblk = (N + 3) / 4;   // node-parallel blocks (1 wave/node)

    k_easeg<<<(N * 32 + 255) / 256, 256, 0, stream>>>(ea, cidx, row_ptr, N, easum);

    // ---------------- conv1: H=2, HC=128 ----------------
    k_xw<128, false><<<dim3(mt, 2), 256, 0, stream>>>(x, N, Wl1, bl1, Wr1, br1, xlb, xrb);
    k_ee<128><<<dim3(mt, 2), 256, 0, stream>>>(easum, N, We1, EEself);
    k_fused<2><<<et, 256, 0, stream>>>(xlb, xrb, ea, cidx, s_csr, d_csr, E, We1, att1, alpha);
    k_aggr<2, true, true><<<nblk, 256, 0, stream>>>(xlb, xrb, EEself, deg, att1, s_csr,
                                                    row_ptr, alpha, bias1, N, h1b);

    // ---------------- conv2: H=3, HC=192 ----------------
    k_xw<192, true><<<dim3(mt, 3), 256, 0, stream>>>(h1b, N, Wl2, bl2, Wr2, br2, xlb, xrb);
    k_ee<192><<<dim3(mt, 3), 256, 0, stream>>>(easum, N, We2, EEself);
    k_fused<3><<<et, 256, 0, stream>>>(xlb, xrb, ea, cidx, s_csr, d_csr, E, We2, att2, alpha);
    k_aggr<3, true, false><<<nblk, 256, 0, stream>>>(xlb, xrb, EEself, deg, att2, s_csr,
                                                     row_ptr, alpha, bias2, N, h2);

    k_pool<<<(N + 127) / 128, 192, 0, stream>>>(h2, batch, N, gp);
    k_mlp<<<1, 256, 0, stream>>>(gp, W1, c1, W2, c2, W3, c3, W4, c4, W5, c5, W6, c6,
                                 (float*)d_out);
}

// Round 19
// 697.249 us; speedup vs baseline: 1.1942x; 1.0091x over previous
//
#include <hip/hip_runtime.h>
#include <hip/hip_bf16.h>
#include <math.h>

// ---------------------------------------------------------------------------
// GATv2 x2 + global_add_pool + MLP head.
// xl/xr/h1/EEself as bf16. k_fused: R13-validated MFMA edge kernel, now 128
// edges/block (2 tiles share the staged We). k_xw: MFMA GEMM. Self-logit
// folded into online-softmax aggregation (k_aggr, (256,3)).
// Machine model (R8-R10): waves/SIMD = 256/VGPR; never force 4 waves/EU on
// fat kernels. k_fused bank conflicts are latency-hidden (R16 proof).
// ---------------------------------------------------------------------------

typedef __attribute__((ext_vector_type(8))) short short8v;
typedef __attribute__((ext_vector_type(4))) float f32x4;

__device__ __forceinline__ unsigned short f2bf(float f) {
    union { float f; unsigned u; } v; v.f = f;
    unsigned r = v.u + 0x7fff + ((v.u >> 16) & 1);
    return (unsigned short)(r >> 16);
}
__device__ __forceinline__ float bf2f(unsigned short b) {
    union { unsigned u; float f; } v; v.u = ((unsigned)b) << 16;
    return v.f;
}

__device__ __forceinline__ int xcd_swizzle(int bid, int nwg) {
    int sq = nwg >> 3, sr = nwg & 7;
    int xcd = bid & 7, idx = bid >> 3;
    return (xcd < sr ? xcd * (sq + 1) : sr * (sq + 1) + (xcd - sr) * sq) + idx;
}

__global__ void k_deg(const int* __restrict__ dst, int E, int* __restrict__ deg) {
    int e = blockIdx.x * blockDim.x + threadIdx.x;
    if (e < E) atomicAdd(&deg[dst[e]], 1);
}

// ---- multi-block exclusive scan: deg[N] -> row_ptr[N+1], woff[N] ----------
__global__ void k_scan1(const int* __restrict__ deg, int N,
                        int* __restrict__ incl, int* __restrict__ bsum) {
    __shared__ int ws4[4];
    const int tid = threadIdx.x;
    const int lane = tid & 63, w = tid >> 6;
    const int base = blockIdx.x * 2048;
    int v[8];
    int s = 0;
#pragma unroll
    for (int j = 0; j < 8; ++j) {
        int i = base + tid * 8 + j;
        v[j] = (i < N) ? deg[i] : 0;
        s += v[j];
    }
    int ps = s;
#pragma unroll
    for (int off = 1; off < 64; off <<= 1) {
        int t = __shfl_up(ps, off);
        if (lane >= off) ps += t;
    }
    if (lane == 63) ws4[w] = ps;
    __syncthreads();
    int woffs = 0;
#pragma unroll
    for (int k = 0; k < 4; ++k)
        if (k < w) woffs += ws4[k];
    int run = ps - s + woffs;
#pragma unroll
    for (int j = 0; j < 8; ++j) {
        run += v[j];
        int i = base + tid * 8 + j;
        if (i < N) incl[i] = run;
    }
    if (tid == 255) bsum[blockIdx.x] = run;
}

__global__ void k_scan2(int* __restrict__ bsum, int nb) {
    if (threadIdx.x == 0) {
        int c = 0;
        for (int k = 0; k < nb; ++k) { int t = bsum[k]; bsum[k] = c; c += t; }
    }
}

__global__ void k_scan3(const int* __restrict__ incl, const int* __restrict__ deg,
                        const int* __restrict__ boff, int N,
                        int* __restrict__ row_ptr, int* __restrict__ woff) {
    int i = blockIdx.x * blockDim.x + threadIdx.x;
    if (i < N) {
        int v = incl[i] + boff[i >> 11];
        row_ptr[i + 1] = v;
        woff[i] = v - deg[i];
        if (i == 0) row_ptr[0] = 0;
    }
}

// scatter edges into CSR order; also materialize src/dst in CSR order
__global__ void k_scatter(const int* __restrict__ src, const int* __restrict__ dst,
                          int E, int* __restrict__ woff, int* __restrict__ cidx,
                          int* __restrict__ s_csr, int* __restrict__ d_csr) {
    int e = blockIdx.x * blockDim.x + threadIdx.x;
    if (e < E) {
        int d = dst[e];
        int p = atomicAdd(&woff[d], 1);
        cidx[p] = e;
        s_csr[p] = src[e];
        d_csr[p] = d;
    }
}

// segmented sum of edge attrs per dst (CSR order): 32-lane group per node
__global__ void k_easeg(const float* __restrict__ ea, const int* __restrict__ cidx,
                        const int* __restrict__ row_ptr, int N,
                        float* __restrict__ easum) {
    const int t = blockIdx.x * blockDim.x + threadIdx.x;
    const int w = t >> 5;
    const int lane = threadIdx.x & 31;
    if (w >= N) return;
    const int beg = row_ptr[w], end = row_ptr[w + 1];
    float s = 0.f;
    for (int i = beg; i < end; ++i) {
        int e = cidx[i];
        s += ea[(size_t)e * 32 + lane];
    }
    easum[(size_t)w * 32 + lane] = s;
}

// ---- MFMA GEMM: {xl,xr}[n][col] = in[n][:128] . W{l,r}[:, col] + b ---------
// Block: 64 nodes x 64 cols, both mats. Wave w owns nodes [w*16, w*16+16).
// INBF: input is bf16 (h1 mirror) -> A-frag is a direct 16B vector load.
template <int HC, bool INBF>
__global__ __launch_bounds__(256, 2) void k_xw(
        const void* __restrict__ in_, int N,
        const float* __restrict__ Wl, const float* __restrict__ bl,
        const float* __restrict__ Wr, const float* __restrict__ br,
        unsigned short* __restrict__ outl, unsigned short* __restrict__ outr) {
    __shared__ __align__(16) unsigned short Wsb[64][136];  // [c][k], +8 pad
    const int tid = threadIdx.x;
    const int m0 = blockIdx.x * 64;
    const int cc0 = blockIdx.y * 64;

    const int lane = tid & 63;
    const int w = tid >> 6;
    const int lm = lane & 15;
    const int lk = lane >> 4;

    // A fragments: this lane's node row, 4 K-chunks of 32 (bf16)
    int node_in = m0 + w * 16 + lm;
    if (node_in >= N) node_in = N - 1;
    short8v afrag[4];
#pragma unroll
    for (int kc = 0; kc < 4; ++kc) {
        if constexpr (INBF) {
            const unsigned short* in = (const unsigned short*)in_;
            afrag[kc] = *(const short8v*)&in[(size_t)node_in * 128 + kc * 32 + lk * 8];
        } else {
            const float* in = (const float*)in_;
            const float4* ap = (const float4*)(in + (size_t)node_in * 128 + kc * 32 + lk * 8);
            float4 v0 = ap[0], v1 = ap[1];
            afrag[kc][0] = (short)f2bf(v0.x); afrag[kc][1] = (short)f2bf(v0.y);
            afrag[kc][2] = (short)f2bf(v0.z); afrag[kc][3] = (short)f2bf(v0.w);
            afrag[kc][4] = (short)f2bf(v1.x); afrag[kc][5] = (short)f2bf(v1.y);
            afrag[kc][6] = (short)f2bf(v1.z); afrag[kc][7] = (short)f2bf(v1.w);
        }
    }

#pragma unroll
    for (int mat = 0; mat < 2; ++mat) {
        const float* W = mat ? Wr : Wl;
        const float* b = mat ? br : bl;
        unsigned short* out = mat ? outr : outl;
        __syncthreads();  // prev-mat reads done before restaging
        // stage W cols cc0..cc0+63 as bf16 col-major: Wsb[c][k]
        for (int i4 = tid; i4 < 128 * 16; i4 += 256) {
            int k = i4 >> 4, c4 = i4 & 15;
            float4 v = *(const float4*)&W[(size_t)k * HC + cc0 + c4 * 4];
            Wsb[c4 * 4 + 0][k] = f2bf(v.x);
            Wsb[c4 * 4 + 1][k] = f2bf(v.y);
            Wsb[c4 * 4 + 2][k] = f2bf(v.z);
            Wsb[c4 * 4 + 3][k] = f2bf(v.w);
        }
        __syncthreads();

#pragma unroll
        for (int cg = 0; cg < 4; ++cg) {
            f32x4 acc = {0.f, 0.f, 0.f, 0.f};
#pragma unroll
            for (int kc = 0; kc < 4; ++kc) {
                short8v bfrag = *(const short8v*)&Wsb[cg * 16 + lm][kc * 32 + lk * 8];
                acc = __builtin_amdgcn_mfma_f32_16x16x32_bf16(afrag[kc], bfrag, acc, 0, 0, 0);
            }
            const int col = cc0 + cg * 16 + lm;   // this lane's D column
            const float bb = b[col];
#pragma unroll
            for (int r = 0; r < 4; ++r) {
                int n = m0 + w * 16 + lk * 4 + r;  // this lane's 4 D rows
                if (n < N) out[(size_t)n * HC + col] = f2bf(acc[r] + bb);
            }
        }
    }
}

// ---- EE GEMM (self-loop path): out[m][col] = A[m][:32] . We[:, col] (bf16) -
template <int HC>
__global__ __launch_bounds__(256, 2) void k_ee(
        const float* __restrict__ A, int M,
        const float* __restrict__ We,
        unsigned short* __restrict__ out) {
    __shared__ float As[32][68];
    __shared__ float Ws[32][64];
    const int tid = threadIdx.x;
    const int m0 = blockIdx.x * 64;
    const int cc = blockIdx.y;

#pragma unroll
    for (int t = 0; t < 2; ++t) {
        int idx4 = tid + t * 256;
        int r = idx4 >> 3, q = idx4 & 7;
        int n = m0 + r;
        float4 v = make_float4(0.f, 0.f, 0.f, 0.f);
        if (n < M) v = ((const float4*)A)[(size_t)n * 8 + q];
        As[q * 4 + 0][r] = v.x;
        As[q * 4 + 1][r] = v.y;
        As[q * 4 + 2][r] = v.z;
        As[q * 4 + 3][r] = v.w;
    }
#pragma unroll
    for (int i = tid; i < 32 * 64; i += 256) {
        int k = i >> 6, c = i & 63;
        Ws[k][c] = We[(size_t)k * HC + cc * 64 + c];
    }
    __syncthreads();

    const int rm = tid >> 4, rn = tid & 15;
    float acc[4][4];
#pragma unroll
    for (int i = 0; i < 4; ++i)
#pragma unroll
        for (int j = 0; j < 4; ++j) acc[i][j] = 0.f;
#pragma unroll
    for (int k = 0; k < 32; ++k) {
        float4 a = *(const float4*)&As[k][rm * 4];
        float4 bv = *(const float4*)&Ws[k][rn * 4];
        acc[0][0] += a.x * bv.x; acc[0][1] += a.x * bv.y;
        acc[0][2] += a.x * bv.z; acc[0][3] += a.x * bv.w;
        acc[1][0] += a.y * bv.x; acc[1][1] += a.y * bv.y;
        acc[1][2] += a.y * bv.z; acc[1][3] += a.y * bv.w;
        acc[2][0] += a.z * bv.x; acc[2][1] += a.z * bv.y;
        acc[2][2] += a.z * bv.z; acc[2][3] += a.z * bv.w;
        acc[3][0] += a.w * bv.x; acc[3][1] += a.w * bv.y;
        acc[3][2] += a.w * bv.z; acc[3][3] += a.w * bv.w;
    }
#pragma unroll
    for (int i = 0; i < 4; ++i) {
        int n = m0 + rm * 4 + i;
        if (n < M) {
            ushort4 o;
            o.x = f2bf(acc[i][0]);
            o.y = f2bf(acc[i][1]);
            o.z = f2bf(acc[i][2]);
            o.w = f2bf(acc[i][3]);
            *(ushort4*)&out[(size_t)n * HC + cc * 64 + rn * 4] = o;
        }
    }
}

// ---- fused edge logits in CSR order, MFMA (R13-validated core) -------------
// 128 edges/block (2 tiles of 64 share the staged We). 4 waves; per tile wave
// w owns edges [t*64 + w*16, +16).
// A-frag: lane holds ea[edge][k = (l>>4)*8 + j] (bf16).
// B-frag: Wsb[col][k0..k0+7] (transposed bf16 LDS tile, one ds_read_b128).
// D: lane holds 4 edges (row=(l>>4)*4+r) x 1 col (l&15) -> column-coalesced
// xl/xr gathers (16 lm-lanes read consecutive cols of the same edge row).
template <int H>
__global__ __launch_bounds__(256, 2) void k_fused(
        const unsigned short* __restrict__ xlb, const unsigned short* __restrict__ xrb,
        const float* __restrict__ ea,
        const int* __restrict__ cidx, const int* __restrict__ s_csr,
        const int* __restrict__ d_csr, int E,
        const float* __restrict__ We, const float* __restrict__ att,
        float* __restrict__ alpha) {
    constexpr int HC = H * 64;
    __shared__ __align__(16) unsigned short Wsb[HC][40];  // [col][k], 80B rows
    __shared__ int Es[128], Ss[128], Ds[128];
    const int tid = threadIdx.x;
    const int wg = xcd_swizzle(blockIdx.x, gridDim.x);
    const int i0 = wg * 128;

    if (tid < 128) {
        int i = i0 + tid;
        bool ok = i < E;
        Es[tid] = ok ? cidx[i] : 0;
        Ss[tid] = ok ? s_csr[i] : 0;
        Ds[tid] = ok ? d_csr[i] : 0;
    }
    // stage We transposed to bf16: Wsb[c][k]
    for (int idx4 = tid; idx4 < 32 * (HC / 4); idx4 += 256) {
        int k = idx4 / (HC / 4), c4 = idx4 % (HC / 4);
        float4 v = ((const float4*)We)[idx4];
        Wsb[c4 * 4 + 0][k] = f2bf(v.x);
        Wsb[c4 * 4 + 1][k] = f2bf(v.y);
        Wsb[c4 * 4 + 2][k] = f2bf(v.z);
        Wsb[c4 * 4 + 3][k] = f2bf(v.w);
    }
    __syncthreads();

    const int lane = tid & 63;
    const int w = tid >> 6;
    const int lm = lane & 15;   // A row (edge) / B,D col
    const int lk = lane >> 4;   // k-chunk / D row-group
    const int k0 = lk * 8;

#pragma unroll
    for (int t = 0; t < 2; ++t) {
        const int tb = t * 64;
        // A fragment: this wave's 16 edges x K=32 (bf16)
        short8v afrag;
        {
            int eidx = Es[tb + w * 16 + lm];
            const float4* ap = (const float4*)(ea + (size_t)eidx * 32 + k0);
            float4 v0 = ap[0], v1 = ap[1];
            afrag[0] = (short)f2bf(v0.x); afrag[1] = (short)f2bf(v0.y);
            afrag[2] = (short)f2bf(v0.z); afrag[3] = (short)f2bf(v0.w);
            afrag[4] = (short)f2bf(v1.x); afrag[5] = (short)f2bf(v1.y);
            afrag[6] = (short)f2bf(v1.z); afrag[7] = (short)f2bf(v1.w);
        }
        // the 4 edges this lane consumes from D (rows lk*4+r)
        int sN[4], dN[4], gOk[4];
#pragma unroll
        for (int r = 0; r < 4; ++r) {
            int el = tb + w * 16 + lk * 4 + r;
            sN[r] = Ss[el];
            dN[r] = Ds[el];
            gOk[r] = (i0 + el) < E;
        }

#pragma unroll
        for (int cc = 0; cc < H; ++cc) {
            float part[4] = {0.f, 0.f, 0.f, 0.f};
#pragma unroll
            for (int cg = 0; cg < 4; ++cg) {
                const int col = cc * 64 + cg * 16 + lm;
                short8v bfrag = *(const short8v*)&Wsb[col][k0];
                f32x4 dacc = {0.f, 0.f, 0.f, 0.f};
                dacc = __builtin_amdgcn_mfma_f32_16x16x32_bf16(afrag, bfrag, dacc, 0, 0, 0);
                float attv = att[col];
#pragma unroll
                for (int r = 0; r < 4; ++r) {
                    float xa = bf2f(xlb[(size_t)sN[r] * HC + col]);
                    float xb = bf2f(xrb[(size_t)dN[r] * HC + col]);
                    float mv = xa + xb + dacc[r];
                    mv = mv > 0.f ? mv : 0.2f * mv;
                    part[r] += mv * attv;
                }
            }
            // reduce over the 16 cols held by this lane-group
#pragma unroll
            for (int off = 1; off < 16; off <<= 1)
#pragma unroll
                for (int r = 0; r < 4; ++r) part[r] += __shfl_xor(part[r], off);
            if (lm == 0) {
#pragma unroll
                for (int r = 0; r < 4; ++r) {
                    if (gOk[r]) {
                        int gi = i0 + tb + w * 16 + lk * 4 + r;
                        alpha[(size_t)gi * H + cc] = part[r];
                    }
                }
            }
        }
    }
}

// online-softmax aggregate over CSR segment, self-logit computed inline.
// One wave per node, lane = channel, 4-edge unroll; gathers as bf16.
// OUTBF: store output as bf16 (h1 mirror for conv2's k_xw).
template <int H, bool RELU, bool OUTBF>
__global__ __launch_bounds__(256, 3) void k_aggr(
        const unsigned short* __restrict__ xlb, const unsigned short* __restrict__ xrb,
        const unsigned short* __restrict__ EEself, const int* __restrict__ deg,
        const float* __restrict__ att,
        const int* __restrict__ s_csr, const int* __restrict__ row_ptr,
        const float* __restrict__ alpha,
        const float* __restrict__ bias, int Nn,
        void* __restrict__ out_) {
    constexpr int HC = H * 64;
    const int lane = threadIdx.x & 63;
    const int wg = xcd_swizzle(blockIdx.x, gridDim.x);
    const int n = wg * 4 + ((int)threadIdx.x >> 6);
    if (n >= Nn) return;

    // ---- self-loop logit, seeds the online softmax ----
    float m[H], den[H], acc[H];
    {
        int dg = deg[n];
        float inv = 1.f / (float)(dg > 0 ? dg : 1);
        float al[H];
#pragma unroll
        for (int h = 0; h < H; ++h) {
            float xlv = bf2f(xlb[(size_t)n * HC + h * 64 + lane]);
            float v = xlv + bf2f(xrb[(size_t)n * HC + h * 64 + lane])
                    + bf2f(EEself[(size_t)n * HC + h * 64 + lane]) * inv;
            v = v > 0.f ? v : 0.2f * v;
            al[h] = v * att[h * 64 + lane];
            acc[h] = xlv;
        }
#pragma unroll
        for (int off = 1; off < 64; off <<= 1)
#pragma unroll
            for (int h = 0; h < H; ++h) al[h] += __shfl_xor(al[h], off);
#pragma unroll
        for (int h = 0; h < H; ++h) { m[h] = al[h]; den[h] = 1.f; }
    }

    const int beg = row_ptr[n], end = row_ptr[n + 1];
    int i = beg;
    for (; i + 3 < end; i += 4) {
        int s0 = s_csr[i], s1 = s_csr[i + 1], s2 = s_csr[i + 2], s3 = s_csr[i + 3];
        float a0[H], a1[H], a2[H], a3[H], xv0[H], xv1[H], xv2[H], xv3[H];
#pragma unroll
        for (int h = 0; h < H; ++h) {
            a0[h] = alpha[(size_t)i * H + h];
            a1[h] = alpha[(size_t)(i + 1) * H + h];
            a2[h] = alpha[(size_t)(i + 2) * H + h];
            a3[h] = alpha[(size_t)(i + 3) * H + h];
            xv0[h] = bf2f(xlb[(size_t)s0 * HC + h * 64 + lane]);
            xv1[h] = bf2f(xlb[(size_t)s1 * HC + h * 64 + lane]);
            xv2[h] = bf2f(xlb[(size_t)s2 * HC + h * 64 + lane]);
            xv3[h] = bf2f(xlb[(size_t)s3 * HC + h * 64 + lane]);
        }
#pragma unroll
        for (int h = 0; h < H; ++h) {
            float mx01 = fmaxf(a0[h], a1[h]);
            float mx23 = fmaxf(a2[h], a3[h]);
            float nm = fmaxf(m[h], fmaxf(mx01, mx23));
            float corr = __expf(m[h] - nm);
            float p0 = __expf(a0[h] - nm);
            float p1 = __expf(a1[h] - nm);
            float p2 = __expf(a2[h] - nm);
            float p3 = __expf(a3[h] - nm);
            den[h] = den[h] * corr + (p0 + p1) + (p2 + p3);
            acc[h] = acc[h] * corr + (p0 * xv0[h] + p1 * xv1[h])
                                   + (p2 * xv2[h] + p3 * xv3[h]);
            m[h] = nm;
        }
    }
    for (; i < end; ++i) {
        int s = s_csr[i];
#pragma unroll
        for (int h = 0; h < H; ++h) {
            float a = alpha[(size_t)i * H + h];
            float xv = bf2f(xlb[(size_t)s * HC + h * 64 + lane]);
            float nm = fmaxf(m[h], a);
            float corr = __expf(m[h] - nm);
            float p = __expf(a - nm);
            den[h] = den[h] * corr + p;
            acc[h] = acc[h] * corr + p * xv;
            m[h] = nm;
        }
    }
#pragma unroll
    for (int h = 0; h < H; ++h) {
        float r = acc[h] / den[h] + bias[h * 64 + lane];
        if (RELU) r = r > 0.f ? r : 0.01f * r;
        if constexpr (OUTBF)
            ((unsigned short*)out_)[(size_t)n * HC + h * 64 + lane] = f2bf(r);
        else
            ((float*)out_)[(size_t)n * HC + h * 64 + lane] = r;
    }
}

// global_add_pool over sorted batch
__global__ void k_pool(const float* __restrict__ h2, const int* __restrict__ batch,
                       int Nn, float* __restrict__ g) {
    const int c = threadIdx.x;  // 0..191
    const int n0 = blockIdx.x * 128;
    if (n0 >= Nn) return;
    const int n1 = (n0 + 128 < Nn) ? n0 + 128 : Nn;
    float s = 0.f;
    int cur = batch[n0];
    for (int n = n0; n < n1; ++n) {
        int b = batch[n];
        if (b != cur) {
            atomicAdd(&g[cur * 192 + c], s);
            s = 0.f;
            cur = b;
        }
        s += h2[(size_t)n * 192 + c];
    }
    atomicAdd(&g[cur * 192 + c], s);
}

__global__ void k_mlp(const float* __restrict__ g,
                      const float* W1, const float* c1, const float* W2, const float* c2,
                      const float* W3, const float* c3, const float* W4, const float* c4,
                      const float* W5, const float* c5, const float* W6, const float* c6,
                      float* __restrict__ out) {
    __shared__ float t0[8 * 192];
    __shared__ float t1[8 * 64];
    __shared__ float t2[8 * 32];
    __shared__ float t3[8 * 16];
    __shared__ float t4[8 * 8];
    const int tid = threadIdx.x;
    for (int i = tid; i < 8 * 192; i += 256) t0[i] = g[i];
    __syncthreads();
    for (int i = tid; i < 8 * 64; i += 256) {
        int r = i >> 6, c = i & 63;
        float s = c1[c];
        for (int k = 0; k < 192; ++k) s += t0[r * 192 + k] * W1[k * 64 + c];
        t1[i] = s > 0.f ? s : 0.01f * s;
    }
    __syncthreads();
    for (int i = tid; i < 8 * 32; i += 256) {
        int r = i >> 5, c = i & 31;
        float s = c2[c];
        for (int k = 0; k < 64; ++k) s += t1[r * 64 + k] * W2[k * 32 + c];
        t2[i] = s > 0.f ? s : 0.01f * s;
    }
    __syncthreads();
    for (int i = tid; i < 8 * 16; i += 256) {
        int r = i >> 4, c = i & 15;
        float s = c3[c];
        for (int k = 0; k < 32; ++k) s += t2[r * 32 + k] * W3[k * 16 + c];
        t3[i] = s > 0.f ? s : 0.01f * s;
    }
    __syncthreads();
    for (int i = tid; i < 8 * 8; i += 256) {
        int r = i >> 3, c = i & 7;
        float s = c4[c];
        for (int k = 0; k < 16; ++k) s += t3[r * 16 + k] * W4[k * 8 + c];
        t4[i] = s > 0.f ? s : 0.01f * s;
    }
    __syncthreads();
    if (tid < 8) {
        float s = c5[0];
        for (int k = 0; k < 8; ++k) s += t4[tid * 8 + k] * W5[k];
        s = s * W6[0] + c6[0];
        out[tid] = s;
    }
}

extern "C" void kernel_launch(void* const* d_in, const int* in_sizes, int n_in,
                              void* d_out, int out_size, void* d_ws, size_t ws_size,
                              hipStream_t stream) {
    const float* x     = (const float*)d_in[0];
    const int*   eidx  = (const int*)d_in[1];
    const float* ea    = (const float*)d_in[2];
    const int*   batch = (const int*)d_in[3];
    const float* Wl1 = (const float*)d_in[4];
    const float* bl1 = (const float*)d_in[5];
    const float* Wr1 = (const float*)d_in[6];
    const float* br1 = (const float*)d_in[7];
    const float* We1 = (const float*)d_in[8];
    const float* att1 = (const float*)d_in[9];
    const float* bias1 = (const float*)d_in[10];
    const float* Wl2 = (const float*)d_in[11];
    const float* bl2 = (const float*)d_in[12];
    const float* Wr2 = (const float*)d_in[13];
    const float* br2 = (const float*)d_in[14];
    const float* We2 = (const float*)d_in[15];
    const float* att2 = (const float*)d_in[16];
    const float* bias2 = (const float*)d_in[17];
    const float* W1 = (const float*)d_in[18];
    const float* c1 = (const float*)d_in[19];
    const float* W2 = (const float*)d_in[20];
    const float* c2 = (const float*)d_in[21];
    const float* W3 = (const float*)d_in[22];
    const float* c3 = (const float*)d_in[23];
    const float* W4 = (const float*)d_in[24];
    const float* c4 = (const float*)d_in[25];
    const float* W5 = (const float*)d_in[26];
    const float* c5 = (const float*)d_in[27];
    const float* W6 = (const float*)d_in[28];
    const float* c6 = (const float*)d_in[29];

    const int N = in_sizes[0] / 128;
    const int E = in_sizes[1] / 2;
    const int* srcs = eidx;
    const int* dsts = eidx + E;

    char* p = (char*)d_ws;
    auto alloc = [&](size_t bytes) -> char* {
        char* r = p;
        p += (bytes + 255) & ~(size_t)255;
        return r;
    };
    int*            deg     = (int*)alloc((size_t)N * 4);
    int*            row_ptr = (int*)alloc((size_t)(N + 1) * 4);
    int*            woff    = (int*)alloc((size_t)N * 4);
    int*            cidx    = (int*)alloc((size_t)E * 4);
    int*            s_csr   = (int*)alloc((size_t)E * 4);
    int*            d_csr   = (int*)alloc((size_t)E * 4);
    int*            incl    = (int*)alloc((size_t)N * 4);
    int*            bsum    = (int*)alloc(64 * 4);
    float*          easum   = (float*)alloc((size_t)N * 32 * 4);
    unsigned short* EEself  = (unsigned short*)alloc((size_t)N * 192 * 2);
    unsigned short* xlb     = (unsigned short*)alloc((size_t)N * 192 * 2);
    unsigned short* xrb     = (unsigned short*)alloc((size_t)N * 192 * 2);
    unsigned short* h1b     = (unsigned short*)alloc((size_t)N * 128 * 2);
    float*          h2      = (float*)alloc((size_t)N * 192 * 4);
    float*          alpha   = (float*)alloc((size_t)E * 3 * 4);
    float*          gp      = (float*)alloc(8 * 192 * 4);

    hipMemsetAsync(deg, 0, (size_t)N * 4, stream);
    hipMemsetAsync(gp, 0, 8 * 192 * 4, stream);

    // CSR build
    const int nb = (N + 2047) / 2048;
    k_deg<<<(E + 255) / 256, 256, 0, stream>>>(dsts, E, deg);
    k_scan1<<<nb, 256, 0, stream>>>(deg, N, incl, bsum);
    k_scan2<<<1, 64, 0, stream>>>(bsum, nb);
    k_scan3<<<(N + 255) / 256, 256, 0, stream>>>(incl, deg, bsum, N, row_ptr, woff);
    k_scatter<<<(E + 255) / 256, 256, 0, stream>>>(srcs, dsts, E, woff, cidx, s_csr, d_csr);

    const int mt = (N + 63) / 64;     // GEMM row tiles
    const int et = (E + 127) / 128;   // fused edge tiles (128 edges/block)
    const int nblk = (N + 3) / 4;     // node-parallel blocks (1 wave/node)

    k_easeg<<<(N * 32 + 255) / 256, 256, 0, stream>>>(ea, cidx, row_ptr, N, easum);

    // ---------------- conv1: H=2, HC=128 ----------------
    k_xw<128, false><<<dim3(mt, 2), 256, 0, stream>>>(x, N, Wl1, bl1, Wr1, br1, xlb, xrb);
    k_ee<128><<<dim3(mt, 2), 256, 0, stream>>>(easum, N, We1, EEself);
    k_fused<2><<<et, 256, 0, stream>>>(xlb, xrb, ea, cidx, s_csr, d_csr, E, We1, att1, alpha);
    k_aggr<2, true, true><<<nblk, 256, 0, stream>>>(xlb, xrb, EEself, deg, att1, s_csr,
                                                    row_ptr, alpha, bias1, N, h1b);

    // ---------------- conv2: H=3, HC=192 ----------------
    k_xw<192, true><<<dim3(mt, 3), 256, 0, stream>>>(h1b, N, Wl2, bl2, Wr2, br2, xlb, xrb);
    k_ee<192><<<dim3(mt, 3), 256, 0, stream>>>(easum, N, We2, EEself);
    k_fused<3><<<et, 256, 0, stream>>>(xlb, xrb, ea, cidx, s_csr, d_csr, E, We2, att2, alpha);
    k_aggr<3, true, false><<<nblk, 256, 0, stream>>>(xlb, xrb, EEself, deg, att2, s_csr,
                                                     row_ptr, alpha, bias2, N, h2);

    k_pool<<<(N + 127) / 128, 192, 0, stream>>>(h2, batch, N, gp);
    k_mlp<<<1, 256, 0, stream>>>(gp, W1, c1, W2, c2, W3, c3, W4, c4, W5, c5, W6, c6,
                                 (float*)d_out);
}